// Round 1
// baseline (483.621 us; speedup 1.0000x reference)
//
#include <hip/hip_runtime.h>
#include <math.h>

// Problem constants
#define B_ROWS 16384      // 8*2048 batch rows
#define IDIM   1024
#define ODIM   1024
#define NGRID  9          // NUM_SEGMENTS + 1
#define KAUG   2048       // two weighted copies of x along K
#define MT_MAX 137        // max padded M-tiles: ceil((16384 + 9*127)/128)
#define MPAD_MAX (MT_MAX*128)

typedef __attribute__((ext_vector_type(8))) short frag8;   // 8 x bf16 (4 VGPRs)
typedef __attribute__((ext_vector_type(4))) float f32x4;   // MFMA accumulator

typedef __attribute__((address_space(1))) void gvoid;
typedef __attribute__((address_space(3))) void lvoid;

__device__ __forceinline__ void async_cp16(const void* g, void* l) {
  // 16B/lane global->LDS DMA; LDS dest = wave-uniform base + lane*16
  __builtin_amdgcn_global_load_lds((gvoid*)(void*)g, (lvoid*)l, 16, 0, 0);
}

__device__ __forceinline__ unsigned short f2bf(float f) {
  union { float f; unsigned u; } v; v.f = f;
  unsigned u = v.u;
  u += 0x7fffu + ((u >> 16) & 1u);      // round-to-nearest-even
  return (unsigned short)(u >> 16);
}

// Per-row hat weights: at most 2 nonzero, at segments {s, s+1}
__device__ __forceinline__ void seg_weights(float m, int& sI, float& w0, float& w1) {
  float wsum = 0.f, wg[NGRID];
#pragma unroll
  for (int g = 0; g < NGRID; g++) {
    float gv = -1.f + 0.25f * (float)g;
    float t = 1.f - fabsf(m - gv) * 4.f;   // 1/h = 4
    wg[g] = t > 0.f ? t : 0.f;
    wsum += wg[g];
  }
  int s = (int)floorf((m + 1.f) * 4.f);
  s = s < 0 ? 0 : (s > 7 ? 7 : s);
  float inv = 1.f / (wsum + 1e-8f);
  sI = s;
  w0 = wg[s] * inv;
  w1 = wg[s + 1] * inv;
}

// ---------------- Pass 0: zero bucket counters ----------------
__global__ void zero_meta(int* bucket_cnt) {
  if (threadIdx.x < NGRID) bucket_cnt[threadIdx.x] = 0;
}

// ---------------- Pass 1: row mean -> segment, weights, rank ----------------
__global__ void row_stats(const float* __restrict__ x, float* __restrict__ w0a,
                          float* __restrict__ w1a, int* __restrict__ sidx,
                          int* __restrict__ rank, int* __restrict__ bucket_cnt) {
  int b = blockIdx.x;
  int tid = threadIdx.x;                 // 256 threads
  float4 v = ((const float4*)(x + (size_t)b * IDIM))[tid];
  float s = v.x + v.y + v.z + v.w;
#pragma unroll
  for (int off = 32; off; off >>= 1) s += __shfl_down(s, off, 64);
  __shared__ float ps[4];
  if ((tid & 63) == 0) ps[tid >> 6] = s;
  __syncthreads();
  if (tid == 0) {
    float m = (ps[0] + ps[1] + ps[2] + ps[3]) * (1.0f / (float)IDIM);
    int sI; float w0, w1;
    seg_weights(m, sI, w0, w1);
    w0a[b] = w0; w1a[b] = w1; sidx[b] = sI;
    rank[b] = atomicAdd(&bucket_cnt[sI], 1);
  }
}

// ---------------- Pass 2: bucket offsets (128-padded), tile segs, pad flags ----------------
__global__ void plan_kernel(const int* __restrict__ cnt, int* __restrict__ bucket_off,
                            int* __restrict__ tile_seg, int* __restrict__ row_idx) {
  if (threadIdx.x != 0 || blockIdx.x != 0) return;
  int off = 0, t = 0;
  for (int g = 0; g < NGRID; g++) {
    bucket_off[g] = off;
    int c = cnt[g];
    int nt = (c + 127) >> 7;
    for (int i = 0; i < nt; i++) tile_seg[t++] = g;
    int padded = nt << 7;
    for (int p = off + c; p < off + padded; p++) row_idx[p] = -1;  // padding rows
    off += padded;
  }
  for (; t < MT_MAX; t++) tile_seg[t] = -1;
}

// ---------------- Pass 3: build bf16 augmented A (sorted, weighted) ----------------
__global__ void build_a(const float* __restrict__ x, const float* __restrict__ w0a,
                        const float* __restrict__ w1a, const int* __restrict__ sidx,
                        const int* __restrict__ rank, const int* __restrict__ bucket_off,
                        unsigned short* __restrict__ Aaug, int* __restrict__ row_idx) {
  int b = blockIdx.x;
  int tid = threadIdx.x;                  // 256 threads
  int s = sidx[b];
  int p = bucket_off[s] + rank[b];
  float w0 = w0a[b], w1 = w1a[b];
  if (tid == 0) row_idx[p] = b;
  float4 v = ((const float4*)(x + (size_t)b * IDIM))[tid];
  ushort4 u0, u1;
  u0.x = f2bf(w0 * v.x); u0.y = f2bf(w0 * v.y); u0.z = f2bf(w0 * v.z); u0.w = f2bf(w0 * v.w);
  u1.x = f2bf(w1 * v.x); u1.y = f2bf(w1 * v.y); u1.z = f2bf(w1 * v.z); u1.w = f2bf(w1 * v.w);
  unsigned short* d = Aaug + (size_t)p * KAUG + tid * 4;
  *(ushort4*)d = u0;
  *(ushort4*)(d + IDIM) = u1;
}

// ---------------- Pass 4: coeff fp32 -> bf16 ----------------
__global__ void cvt_coeff(const float* __restrict__ c, unsigned short* __restrict__ cb, int n4) {
  int i = blockIdx.x * blockDim.x + threadIdx.x;
  if (i < n4) {
    float4 v = ((const float4*)c)[i];
    ushort4 o;
    o.x = f2bf(v.x); o.y = f2bf(v.y); o.z = f2bf(v.z); o.w = f2bf(v.w);
    ((ushort4*)cb)[i] = o;
  }
}

// ---------------- Pass 5: MFMA GEMM (m97 structure) ----------------
// C[p, o] = sum_k Aaug[p,k] * Bt[o,k],  Bt[o, k] = coeff_bf16[seg + (k>=1024), o, k&1023]
__global__ void kan_gemm(const unsigned short* __restrict__ Aaug,
                         const unsigned short* __restrict__ Cb,
                         const int* __restrict__ row_idx,
                         const int* __restrict__ tile_seg,
                         const float* __restrict__ bias,
                         float* __restrict__ out) {
  int seg = tile_seg[blockIdx.x];
  if (seg < 0) return;                      // uniform over block: barrier-safe
  __shared__ unsigned short As[128 * 32];   // 8 KB
  __shared__ unsigned short Bs[128 * 32];   // 8 KB

  const int tid  = threadIdx.x;
  const int lane = tid & 63;
  const int wave = tid >> 6;                // 4 waves, 2x2 over 128x128
  const int wm   = wave >> 1;
  const int wn   = wave & 1;
  const size_t rowA0 = (size_t)blockIdx.x * 128;
  const int    colB0 = blockIdx.y * 128;

  const int lrow = lane >> 2;               // 0..15 rows per 1KB issue
  const int lk8  = (lane & 3) * 8;          // bf16 element offset in K-slab

  f32x4 acc[4][4] = {};

  for (int kk = 0; kk < KAUG; kk += 32) {
    int g  = seg + (kk >> 10);              // first or second K-half
    int i0 = kk & (IDIM - 1);
    const unsigned short* gA = Aaug + (rowA0 + lrow) * KAUG + kk + lk8;
    const unsigned short* gB = Cb + ((size_t)(g * ODIM + colB0 + lrow)) * IDIM + i0 + lk8;

    __syncthreads();                        // prior iter's LDS reads complete
#pragma unroll
    for (int t = 0; t < 2; t++) {
      int r0 = (wave * 2 + t) * 16;         // 16 rows (1024 B) per issue
      async_cp16(gA + (size_t)r0 * KAUG, &As[r0 * 32]);
      async_cp16(gB + (size_t)r0 * IDIM, &Bs[r0 * 32]);
    }
    __syncthreads();                        // staging visible (vmcnt drain at barrier)

    frag8 af[4], bfr[4];
#pragma unroll
    for (int mi = 0; mi < 4; mi++)
      af[mi] = *(const frag8*)&As[(wm * 64 + mi * 16 + (lane & 15)) * 32 + (lane >> 4) * 8];
#pragma unroll
    for (int ni = 0; ni < 4; ni++)
      bfr[ni] = *(const frag8*)&Bs[(wn * 64 + ni * 16 + (lane & 15)) * 32 + (lane >> 4) * 8];
#pragma unroll
    for (int mi = 0; mi < 4; mi++)
#pragma unroll
      for (int ni = 0; ni < 4; ni++)
        acc[mi][ni] = __builtin_amdgcn_mfma_f32_16x16x32_bf16(af[mi], bfr[ni], acc[mi][ni], 0, 0, 0);
  }

  // Epilogue: D col = lane&15, row = (lane>>4)*4 + reg  [m89/m91 verified]
  int   col[4]; float bv[4];
#pragma unroll
  for (int ni = 0; ni < 4; ni++) {
    col[ni] = colB0 + wn * 64 + ni * 16 + (lane & 15);
    bv[ni]  = bias[col[ni]];
  }
#pragma unroll
  for (int mi = 0; mi < 4; mi++) {
    int prow = (int)rowA0 + wm * 64 + mi * 16 + (lane >> 4) * 4;
#pragma unroll
    for (int r = 0; r < 4; r++) {
      int orow = row_idx[prow + r];
      if ((unsigned)orow < (unsigned)B_ROWS) {
        float* o = out + (size_t)orow * ODIM;
#pragma unroll
        for (int ni = 0; ni < 4; ni++) o[col[ni]] = acc[mi][ni][r] + bv[ni];
      }
    }
  }
}

// ---------------- Fallback (ws too small): slow fp32, correct ----------------
__global__ void fallback_kernel(const float* __restrict__ x, const float* __restrict__ coeff,
                                const float* __restrict__ bias, float* __restrict__ out) {
  int b = blockIdx.x;
  int tid = threadIdx.x;
  __shared__ float xs[IDIM];
  __shared__ float ps[4];
  __shared__ float mw[2];
  __shared__ int   ms;
  float4 v = ((const float4*)(x + (size_t)b * IDIM))[tid];
  ((float4*)xs)[tid] = v;
  float s = v.x + v.y + v.z + v.w;
#pragma unroll
  for (int off = 32; off; off >>= 1) s += __shfl_down(s, off, 64);
  if ((tid & 63) == 0) ps[tid >> 6] = s;
  __syncthreads();
  if (tid == 0) {
    float m = (ps[0] + ps[1] + ps[2] + ps[3]) * (1.0f / (float)IDIM);
    int sI; float w0, w1;
    seg_weights(m, sI, w0, w1);
    mw[0] = w0; mw[1] = w1; ms = sI;
  }
  __syncthreads();
  float w0 = mw[0], w1 = mw[1]; int sI = ms;
  for (int o = tid; o < ODIM; o += 256) {
    const float* c0 = coeff + ((size_t)sI * ODIM + o) * IDIM;
    const float* c1 = c0 + (size_t)ODIM * IDIM;
    float a0 = 0.f, a1 = 0.f;
    for (int i = 0; i < IDIM; i++) { a0 += xs[i] * c0[i]; a1 += xs[i] * c1[i]; }
    out[(size_t)b * ODIM + o] = w0 * a0 + w1 * a1 + bias[o];
  }
}

extern "C" void kernel_launch(void* const* d_in, const int* in_sizes, int n_in,
                              void* d_out, int out_size, void* d_ws, size_t ws_size,
                              hipStream_t stream) {
  const float* x     = (const float*)d_in[0];
  const float* coeff = (const float*)d_in[1];
  const float* bias  = (const float*)d_in[2];
  float* out = (float*)d_out;

  // Workspace layout (16B-aligned chunks)
  size_t szAaug = (size_t)MPAD_MAX * KAUG * sizeof(unsigned short); // 71,827,456
  size_t szCb   = (size_t)NGRID * ODIM * IDIM * sizeof(unsigned short); // 18,874,368
  size_t o0 = 0;
  unsigned short* Aaug = (unsigned short*)((char*)d_ws + o0); o0 += szAaug;
  unsigned short* Cb   = (unsigned short*)((char*)d_ws + o0); o0 += szCb;
  float* w0a = (float*)((char*)d_ws + o0); o0 += (size_t)B_ROWS * 4;
  float* w1a = (float*)((char*)d_ws + o0); o0 += (size_t)B_ROWS * 4;
  int* sidx  = (int*)((char*)d_ws + o0);   o0 += (size_t)B_ROWS * 4;
  int* rank  = (int*)((char*)d_ws + o0);   o0 += (size_t)B_ROWS * 4;
  int* row_idx = (int*)((char*)d_ws + o0); o0 += (size_t)MPAD_MAX * 4;
  int* bucket_cnt = (int*)((char*)d_ws + o0); o0 += 256;
  int* bucket_off = (int*)((char*)d_ws + o0); o0 += 256;
  int* tile_seg   = (int*)((char*)d_ws + o0); o0 += 1024;

  if (ws_size < o0) {
    // Emergency slow path: no workspace required.
    fallback_kernel<<<B_ROWS, 256, 0, stream>>>(x, coeff, bias, out);
    return;
  }

  zero_meta<<<1, 64, 0, stream>>>(bucket_cnt);
  row_stats<<<B_ROWS, 256, 0, stream>>>(x, w0a, w1a, sidx, rank, bucket_cnt);
  plan_kernel<<<1, 1, 0, stream>>>(bucket_cnt, bucket_off, tile_seg, row_idx);
  build_a<<<B_ROWS, 256, 0, stream>>>(x, w0a, w1a, sidx, rank, bucket_off, Aaug, row_idx);
  int n4 = NGRID * ODIM * IDIM / 4;
  cvt_coeff<<<(n4 + 255) / 256, 256, 0, stream>>>(coeff, Cb, n4);
  kan_gemm<<<dim3(MT_MAX, ODIM / 128), 256, 0, stream>>>(Aaug, Cb, row_idx, tile_seg, bias, out);
}

// Round 2
// 318.075 us; speedup vs baseline: 1.5205x; 1.5205x over previous
//
#include <hip/hip_runtime.h>
#include <math.h>

// Problem constants
#define B_ROWS 16384      // 8*2048 batch rows
#define IDIM   1024
#define ODIM   1024
#define NGRID  9          // NUM_SEGMENTS + 1
#define KAUG   2048       // two weighted copies of x along K
#define MT_MAX 137        // max padded M-tiles: ceil((16384 + 9*127)/128)
#define MPAD_MAX (MT_MAX*128)

#define RS_BLOCKS 256
#define RS_ROWS   (B_ROWS / RS_BLOCKS)   // 64 rows per block

typedef __attribute__((ext_vector_type(8))) short frag8;   // 8 x bf16 (4 VGPRs)
typedef __attribute__((ext_vector_type(4))) float f32x4;   // MFMA accumulator

typedef __attribute__((address_space(1))) void gvoid;
typedef __attribute__((address_space(3))) void lvoid;

__device__ __forceinline__ void async_cp16(const void* g, void* l) {
  // 16B/lane global->LDS DMA; LDS dest = wave-uniform base + lane*16
  __builtin_amdgcn_global_load_lds((gvoid*)(void*)g, (lvoid*)l, 16, 0, 0);
}

__device__ __forceinline__ unsigned short f2bf(float f) {
  union { float f; unsigned u; } v; v.f = f;
  unsigned u = v.u;
  u += 0x7fffu + ((u >> 16) & 1u);      // round-to-nearest-even
  return (unsigned short)(u >> 16);
}

// Per-row hat weights: at most 2 nonzero, at segments {s, s+1}
__device__ __forceinline__ void seg_weights(float m, int& sI, float& w0, float& w1) {
  float wsum = 0.f, wg[NGRID];
#pragma unroll
  for (int g = 0; g < NGRID; g++) {
    float gv = -1.f + 0.25f * (float)g;
    float t = 1.f - fabsf(m - gv) * 4.f;   // 1/h = 4
    wg[g] = t > 0.f ? t : 0.f;
    wsum += wg[g];
  }
  int s = (int)floorf((m + 1.f) * 4.f);
  s = s < 0 ? 0 : (s > 7 ? 7 : s);
  float inv = 1.f / (wsum + 1e-8f);
  sI = s;
  w0 = wg[s] * inv;
  w1 = wg[s + 1] * inv;
}

// ---------------- Pass 0: zero bucket counters ----------------
__global__ void zero_meta(int* bucket_cnt) {
  if (threadIdx.x < NGRID) bucket_cnt[threadIdx.x] = 0;
}

// ---------------- Pass 1: row mean -> segment, weights, rank ----------------
// Two-level atomic aggregation: LDS histogram + local ranks, then <=9 global
// atomics per block (was: 16384 same-address global atomics -> 191 us).
__global__ void row_stats(const float* __restrict__ x, float* __restrict__ w0a,
                          float* __restrict__ w1a, int* __restrict__ sidx,
                          int* __restrict__ rank, int* __restrict__ bucket_cnt) {
  __shared__ int lcnt[NGRID];
  __shared__ int base[NGRID];
  __shared__ int lrank[RS_ROWS];
  __shared__ int lseg[RS_ROWS];
  const int tid  = threadIdx.x;          // 256 threads, 4 waves
  const int lane = tid & 63;
  const int wave = tid >> 6;
  if (tid < NGRID) lcnt[tid] = 0;
  __syncthreads();
  const int row0 = blockIdx.x * RS_ROWS;
#pragma unroll 4
  for (int it = 0; it < RS_ROWS / 4; ++it) {
    int r = it * 4 + wave;               // one wave per row
    int b = row0 + r;
    const float4* xr = (const float4*)(x + (size_t)b * IDIM);
    float s = 0.f;
#pragma unroll
    for (int j = 0; j < 4; j++) {        // 4 independent 16B loads/lane
      float4 v = xr[lane + j * 64];
      s += v.x + v.y + v.z + v.w;
    }
#pragma unroll
    for (int off = 32; off; off >>= 1) s += __shfl_down(s, off, 64);
    if (lane == 0) {
      float m = s * (1.0f / (float)IDIM);
      int sI; float w0, w1;
      seg_weights(m, sI, w0, w1);
      w0a[b] = w0; w1a[b] = w1; sidx[b] = sI;
      lseg[r] = sI;
      lrank[r] = atomicAdd(&lcnt[sI], 1);   // LDS atomic: cheap
    }
  }
  __syncthreads();
  if (tid < NGRID) base[tid] = lcnt[tid] ? atomicAdd(&bucket_cnt[tid], lcnt[tid]) : 0;
  __syncthreads();
  if (tid < RS_ROWS) rank[row0 + tid] = base[lseg[tid]] + lrank[tid];
}

// ---------------- Pass 2: bucket offsets (128-padded), tile segs, pad flags ----------------
__global__ void plan_kernel(const int* __restrict__ cnt, int* __restrict__ bucket_off,
                            int* __restrict__ tile_seg, int* __restrict__ row_idx) {
  __shared__ int offs[NGRID + 1];
  const int tid = threadIdx.x;           // 256 threads, 1 block
  if (tid == 0) {
    int off = 0;
    for (int g = 0; g < NGRID; g++) {
      offs[g] = off;
      off += ((cnt[g] + 127) >> 7) << 7;
    }
    offs[NGRID] = off;
  }
  __syncthreads();
  if (tid < NGRID) bucket_off[tid] = offs[tid];
  for (int t = tid; t < MT_MAX; t += 256) {
    int seg = -1;
#pragma unroll
    for (int g = 0; g < NGRID; g++)
      if (t >= (offs[g] >> 7) && t < (offs[g + 1] >> 7)) seg = g;
    tile_seg[t] = seg;
  }
#pragma unroll
  for (int g = 0; g < NGRID; g++) {
    int lo = offs[g] + cnt[g], hi = offs[g + 1];
    for (int p = lo + tid; p < hi; p += 256) row_idx[p] = -1;  // padding rows
  }
}

// ---------------- Pass 3: build bf16 augmented A (sorted, weighted) ----------------
#define BA_ROWS 8
__global__ void build_a(const float* __restrict__ x, const float* __restrict__ w0a,
                        const float* __restrict__ w1a, const int* __restrict__ sidx,
                        const int* __restrict__ rank, const int* __restrict__ bucket_off,
                        unsigned short* __restrict__ Aaug, int* __restrict__ row_idx) {
  const int tid = threadIdx.x;            // 256 threads
  const int b0 = blockIdx.x * BA_ROWS;
#pragma unroll
  for (int r = 0; r < BA_ROWS; r++) {
    int b = b0 + r;
    int s = sidx[b];
    int p = bucket_off[s] + rank[b];
    float w0 = w0a[b], w1 = w1a[b];
    if (tid == 0) row_idx[p] = b;
    float4 v = ((const float4*)(x + (size_t)b * IDIM))[tid];
    ushort4 u0, u1;
    u0.x = f2bf(w0 * v.x); u0.y = f2bf(w0 * v.y); u0.z = f2bf(w0 * v.z); u0.w = f2bf(w0 * v.w);
    u1.x = f2bf(w1 * v.x); u1.y = f2bf(w1 * v.y); u1.z = f2bf(w1 * v.z); u1.w = f2bf(w1 * v.w);
    unsigned short* d = Aaug + (size_t)p * KAUG + tid * 4;
    *(ushort4*)d = u0;
    *(ushort4*)(d + IDIM) = u1;
  }
}

// ---------------- Pass 4: coeff fp32 -> bf16 ----------------
__global__ void cvt_coeff(const float* __restrict__ c, unsigned short* __restrict__ cb, int n4) {
  int i = blockIdx.x * blockDim.x + threadIdx.x;
  if (i < n4) {
    float4 v = ((const float4*)c)[i];
    ushort4 o;
    o.x = f2bf(v.x); o.y = f2bf(v.y); o.z = f2bf(v.z); o.w = f2bf(v.w);
    ((ushort4*)cb)[i] = o;
  }
}

// ---------------- Pass 5: MFMA GEMM (m97 structure) ----------------
// C[p, o] = sum_k Aaug[p,k] * Bt[o,k],  Bt[o, k] = coeff_bf16[seg + (k>=1024), o, k&1023]
__global__ void kan_gemm(const unsigned short* __restrict__ Aaug,
                         const unsigned short* __restrict__ Cb,
                         const int* __restrict__ row_idx,
                         const int* __restrict__ tile_seg,
                         const float* __restrict__ bias,
                         float* __restrict__ out) {
  int seg = tile_seg[blockIdx.x];
  if (seg < 0) return;                      // uniform over block: barrier-safe
  __shared__ unsigned short As[128 * 32];   // 8 KB
  __shared__ unsigned short Bs[128 * 32];   // 8 KB

  const int tid  = threadIdx.x;
  const int lane = tid & 63;
  const int wave = tid >> 6;                // 4 waves, 2x2 over 128x128
  const int wm   = wave >> 1;
  const int wn   = wave & 1;
  const size_t rowA0 = (size_t)blockIdx.x * 128;
  const int    colB0 = blockIdx.y * 128;

  const int lrow = lane >> 2;               // 0..15 rows per 1KB issue
  const int lk8  = (lane & 3) * 8;          // bf16 element offset in K-slab

  f32x4 acc[4][4] = {};

  for (int kk = 0; kk < KAUG; kk += 32) {
    int g  = seg + (kk >> 10);              // first or second K-half
    int i0 = kk & (IDIM - 1);
    const unsigned short* gA = Aaug + (rowA0 + lrow) * KAUG + kk + lk8;
    const unsigned short* gB = Cb + ((size_t)(g * ODIM + colB0 + lrow)) * IDIM + i0 + lk8;

    __syncthreads();                        // prior iter's LDS reads complete
#pragma unroll
    for (int t = 0; t < 2; t++) {
      int r0 = (wave * 2 + t) * 16;         // 16 rows (1024 B) per issue
      async_cp16(gA + (size_t)r0 * KAUG, &As[r0 * 32]);
      async_cp16(gB + (size_t)r0 * IDIM, &Bs[r0 * 32]);
    }
    __syncthreads();                        // staging visible (vmcnt drain at barrier)

    frag8 af[4], bfr[4];
#pragma unroll
    for (int mi = 0; mi < 4; mi++)
      af[mi] = *(const frag8*)&As[(wm * 64 + mi * 16 + (lane & 15)) * 32 + (lane >> 4) * 8];
#pragma unroll
    for (int ni = 0; ni < 4; ni++)
      bfr[ni] = *(const frag8*)&Bs[(wn * 64 + ni * 16 + (lane & 15)) * 32 + (lane >> 4) * 8];
#pragma unroll
    for (int mi = 0; mi < 4; mi++)
#pragma unroll
      for (int ni = 0; ni < 4; ni++)
        acc[mi][ni] = __builtin_amdgcn_mfma_f32_16x16x32_bf16(af[mi], bfr[ni], acc[mi][ni], 0, 0, 0);
  }

  // Epilogue: D col = lane&15, row = (lane>>4)*4 + reg  [m89/m91 verified]
  int   col[4]; float bv[4];
#pragma unroll
  for (int ni = 0; ni < 4; ni++) {
    col[ni] = colB0 + wn * 64 + ni * 16 + (lane & 15);
    bv[ni]  = bias[col[ni]];
  }
#pragma unroll
  for (int mi = 0; mi < 4; mi++) {
    int prow = (int)rowA0 + wm * 64 + mi * 16 + (lane >> 4) * 4;
#pragma unroll
    for (int r = 0; r < 4; r++) {
      int orow = row_idx[prow + r];
      if ((unsigned)orow < (unsigned)B_ROWS) {
        float* o = out + (size_t)orow * ODIM;
#pragma unroll
        for (int ni = 0; ni < 4; ni++) o[col[ni]] = acc[mi][ni][r] + bv[ni];
      }
    }
  }
}

// ---------------- Fallback (ws too small): slow fp32, correct ----------------
__global__ void fallback_kernel(const float* __restrict__ x, const float* __restrict__ coeff,
                                const float* __restrict__ bias, float* __restrict__ out) {
  int b = blockIdx.x;
  int tid = threadIdx.x;
  __shared__ float xs[IDIM];
  __shared__ float ps[4];
  __shared__ float mw[2];
  __shared__ int   ms;
  float4 v = ((const float4*)(x + (size_t)b * IDIM))[tid];
  ((float4*)xs)[tid] = v;
  float s = v.x + v.y + v.z + v.w;
#pragma unroll
  for (int off = 32; off; off >>= 1) s += __shfl_down(s, off, 64);
  if ((tid & 63) == 0) ps[tid >> 6] = s;
  __syncthreads();
  if (tid == 0) {
    float m = (ps[0] + ps[1] + ps[2] + ps[3]) * (1.0f / (float)IDIM);
    int sI; float w0, w1;
    seg_weights(m, sI, w0, w1);
    mw[0] = w0; mw[1] = w1; ms = sI;
  }
  __syncthreads();
  float w0 = mw[0], w1 = mw[1]; int sI = ms;
  for (int o = tid; o < ODIM; o += 256) {
    const float* c0 = coeff + ((size_t)sI * ODIM + o) * IDIM;
    const float* c1 = c0 + (size_t)ODIM * IDIM;
    float a0 = 0.f, a1 = 0.f;
    for (int i = 0; i < IDIM; i++) { a0 += xs[i] * c0[i]; a1 += xs[i] * c1[i]; }
    out[(size_t)b * ODIM + o] = w0 * a0 + w1 * a1 + bias[o];
  }
}

extern "C" void kernel_launch(void* const* d_in, const int* in_sizes, int n_in,
                              void* d_out, int out_size, void* d_ws, size_t ws_size,
                              hipStream_t stream) {
  const float* x     = (const float*)d_in[0];
  const float* coeff = (const float*)d_in[1];
  const float* bias  = (const float*)d_in[2];
  float* out = (float*)d_out;

  // Workspace layout (16B-aligned chunks)
  size_t szAaug = (size_t)MPAD_MAX * KAUG * sizeof(unsigned short); // 71,827,456
  size_t szCb   = (size_t)NGRID * ODIM * IDIM * sizeof(unsigned short); // 18,874,368
  size_t o0 = 0;
  unsigned short* Aaug = (unsigned short*)((char*)d_ws + o0); o0 += szAaug;
  unsigned short* Cb   = (unsigned short*)((char*)d_ws + o0); o0 += szCb;
  float* w0a = (float*)((char*)d_ws + o0); o0 += (size_t)B_ROWS * 4;
  float* w1a = (float*)((char*)d_ws + o0); o0 += (size_t)B_ROWS * 4;
  int* sidx  = (int*)((char*)d_ws + o0);   o0 += (size_t)B_ROWS * 4;
  int* rank  = (int*)((char*)d_ws + o0);   o0 += (size_t)B_ROWS * 4;
  int* row_idx = (int*)((char*)d_ws + o0); o0 += (size_t)MPAD_MAX * 4;
  int* bucket_cnt = (int*)((char*)d_ws + o0); o0 += 256;
  int* bucket_off = (int*)((char*)d_ws + o0); o0 += 256;
  int* tile_seg   = (int*)((char*)d_ws + o0); o0 += 1024;

  if (ws_size < o0) {
    // Emergency slow path: no workspace required.
    fallback_kernel<<<B_ROWS, 256, 0, stream>>>(x, coeff, bias, out);
    return;
  }

  zero_meta<<<1, 64, 0, stream>>>(bucket_cnt);
  row_stats<<<RS_BLOCKS, 256, 0, stream>>>(x, w0a, w1a, sidx, rank, bucket_cnt);
  plan_kernel<<<1, 256, 0, stream>>>(bucket_cnt, bucket_off, tile_seg, row_idx);
  build_a<<<B_ROWS / BA_ROWS, 256, 0, stream>>>(x, w0a, w1a, sidx, rank, bucket_off, Aaug, row_idx);
  int n4 = NGRID * ODIM * IDIM / 4;
  cvt_coeff<<<(n4 + 255) / 256, 256, 0, stream>>>(coeff, Cb, n4);
  kan_gemm<<<dim3(MT_MAX, ODIM / 128), 256, 0, stream>>>(Aaug, Cb, row_idx, tile_seg, bias, out);
}

// Round 3
// 278.792 us; speedup vs baseline: 1.7347x; 1.1409x over previous
//
#include <hip/hip_runtime.h>
#include <math.h>

// Problem constants
#define B_ROWS 16384      // 8*2048 batch rows
#define IDIM   1024
#define ODIM   1024
#define NGRID  9          // NUM_SEGMENTS + 1
#define MT_MAX 137        // max padded M-tiles: ceil((16384 + 9*127)/128)
#define MPAD_MAX (MT_MAX*128)

#define RS_BLOCKS 256
#define RS_ROWS   (B_ROWS / RS_BLOCKS)   // 64 rows per block

typedef __attribute__((ext_vector_type(8))) short frag8;   // 8 x bf16 (4 VGPRs)
typedef __attribute__((ext_vector_type(4))) float f32x4;   // MFMA accumulator

typedef __attribute__((address_space(1))) void gvoid;
typedef __attribute__((address_space(3))) void lvoid;

__device__ __forceinline__ void async_cp16(const void* g, void* l) {
  // 16B/lane global->LDS DMA; LDS dest = wave-uniform base + lane*16
  __builtin_amdgcn_global_load_lds((gvoid*)(void*)g, (lvoid*)l, 16, 0, 0);
}

__device__ __forceinline__ unsigned short f2bf(float f) {
  union { float f; unsigned u; } v; v.f = f;
  unsigned u = v.u;
  u += 0x7fffu + ((u >> 16) & 1u);      // round-to-nearest-even
  return (unsigned short)(u >> 16);
}

// Per-row hat weights: at most 2 nonzero, at segments {s, s+1}
__device__ __forceinline__ void seg_weights(float m, int& sI, float& w0, float& w1) {
  float wsum = 0.f, wg[NGRID];
#pragma unroll
  for (int g = 0; g < NGRID; g++) {
    float gv = -1.f + 0.25f * (float)g;
    float t = 1.f - fabsf(m - gv) * 4.f;   // 1/h = 4
    wg[g] = t > 0.f ? t : 0.f;
    wsum += wg[g];
  }
  int s = (int)floorf((m + 1.f) * 4.f);
  s = s < 0 ? 0 : (s > 7 ? 7 : s);
  float inv = 1.f / (wsum + 1e-8f);
  sI = s;
  w0 = wg[s] * inv;
  w1 = wg[s + 1] * inv;
}

// ---------------- Pass 0: zero bucket counters ----------------
__global__ void zero_meta(int* bucket_cnt) {
  if (threadIdx.x < NGRID) bucket_cnt[threadIdx.x] = 0;
}

// ---------------- Pass 1: row mean -> segment, weights, rank ----------------
// Two-level atomic aggregation: LDS histogram + local ranks, then <=9 global
// atomics per block.
__global__ void row_stats(const float* __restrict__ x, float* __restrict__ w0a,
                          float* __restrict__ w1a, int* __restrict__ sidx,
                          int* __restrict__ rank, int* __restrict__ bucket_cnt) {
  __shared__ int lcnt[NGRID];
  __shared__ int base[NGRID];
  __shared__ int lrank[RS_ROWS];
  __shared__ int lseg[RS_ROWS];
  const int tid  = threadIdx.x;          // 256 threads, 4 waves
  const int lane = tid & 63;
  const int wave = tid >> 6;
  if (tid < NGRID) lcnt[tid] = 0;
  __syncthreads();
  const int row0 = blockIdx.x * RS_ROWS;
#pragma unroll 4
  for (int it = 0; it < RS_ROWS / 4; ++it) {
    int r = it * 4 + wave;               // one wave per row
    int b = row0 + r;
    const float4* xr = (const float4*)(x + (size_t)b * IDIM);
    float s = 0.f;
#pragma unroll
    for (int j = 0; j < 4; j++) {        // 4 independent 16B loads/lane
      float4 v = xr[lane + j * 64];
      s += v.x + v.y + v.z + v.w;
    }
#pragma unroll
    for (int off = 32; off; off >>= 1) s += __shfl_down(s, off, 64);
    if (lane == 0) {
      float m = s * (1.0f / (float)IDIM);
      int sI; float w0, w1;
      seg_weights(m, sI, w0, w1);
      w0a[b] = w0; w1a[b] = w1; sidx[b] = sI;
      lseg[r] = sI;
      lrank[r] = atomicAdd(&lcnt[sI], 1);   // LDS atomic: cheap
    }
  }
  __syncthreads();
  if (tid < NGRID) base[tid] = lcnt[tid] ? atomicAdd(&bucket_cnt[tid], lcnt[tid]) : 0;
  __syncthreads();
  if (tid < RS_ROWS) rank[row0 + tid] = base[lseg[tid]] + lrank[tid];
}

// ---------------- Pass 2: bucket offsets (128-padded), tile segs, pad flags ----------------
__global__ void plan_kernel(const int* __restrict__ cnt, int* __restrict__ bucket_off,
                            int* __restrict__ tile_seg, int* __restrict__ row_idx) {
  __shared__ int offs[NGRID + 1];
  const int tid = threadIdx.x;           // 256 threads, 1 block
  if (tid == 0) {
    int off = 0;
    for (int g = 0; g < NGRID; g++) {
      offs[g] = off;
      off += ((cnt[g] + 127) >> 7) << 7;
    }
    offs[NGRID] = off;
  }
  __syncthreads();
  if (tid < NGRID) bucket_off[tid] = offs[tid];
  for (int t = tid; t < MT_MAX; t += 256) {
    int seg = -1;
#pragma unroll
    for (int g = 0; g < NGRID; g++)
      if (t >= (offs[g] >> 7) && t < (offs[g + 1] >> 7)) seg = g;
    tile_seg[t] = seg;
  }
#pragma unroll
  for (int g = 0; g < NGRID; g++) {
    int lo = offs[g] + cnt[g], hi = offs[g + 1];
    for (int p = lo + tid; p < hi; p += 256) row_idx[p] = -1;  // padding rows
  }
}

// ---------------- Pass 3: build bf16 sorted X (unweighted) + sorted weights ----------------
#define BA_ROWS 8
__global__ void build_a(const float* __restrict__ x, const float* __restrict__ w0a,
                        const float* __restrict__ w1a, const int* __restrict__ sidx,
                        const int* __restrict__ rank, const int* __restrict__ bucket_off,
                        unsigned short* __restrict__ Xs, float2* __restrict__ ws,
                        int* __restrict__ row_idx) {
  const int tid = threadIdx.x;            // 256 threads
  const int b0 = blockIdx.x * BA_ROWS;
#pragma unroll
  for (int r = 0; r < BA_ROWS; r++) {
    int b = b0 + r;
    int s = sidx[b];
    int p = bucket_off[s] + rank[b];
    if (tid == 0) { row_idx[p] = b; ws[p] = make_float2(w0a[b], w1a[b]); }
    float4 v = ((const float4*)(x + (size_t)b * IDIM))[tid];
    ushort4 u;
    u.x = f2bf(v.x); u.y = f2bf(v.y); u.z = f2bf(v.z); u.w = f2bf(v.w);
    *(ushort4*)(Xs + (size_t)p * IDIM + tid * 4) = u;
  }
}

// ---------------- Pass 4: coeff fp32 -> bf16 ----------------
__global__ void cvt_coeff(const float* __restrict__ c, unsigned short* __restrict__ cb, int n4) {
  int i = blockIdx.x * blockDim.x + threadIdx.x;
  if (i < n4) {
    float4 v = ((const float4*)c)[i];
    ushort4 o;
    o.x = f2bf(v.x); o.y = f2bf(v.y); o.z = f2bf(v.z); o.w = f2bf(v.w);
    ((ushort4*)cb)[i] = o;
  }
}

// ---------------- Pass 5: MFMA GEMM, dual-accumulator ----------------
// acc0 = Xs_tile @ coeff[seg]^T, acc1 = Xs_tile @ coeff[seg+1]^T  (K=1024)
// out[row] = w0[row]*acc0 + w1[row]*acc1 + bias.
// Grid: (8 n-tiles FAST, 137 m-tiles) so the 8 blocks sharing an A M-tile are
// consecutive workgroup IDs -> concurrent on 8 XCDs -> A fetched ~once (L3).
__global__ void __launch_bounds__(256, 2)
kan_gemm(const unsigned short* __restrict__ Xs,
         const unsigned short* __restrict__ Cb,
         const int* __restrict__ row_idx,
         const int* __restrict__ tile_seg,
         const float2* __restrict__ ws,
         const float* __restrict__ bias,
         float* __restrict__ out) {
  int seg = tile_seg[blockIdx.y];
  if (seg < 0) return;                      // uniform over block: barrier-safe
  __shared__ unsigned short As[128 * 32];   // 8 KB
  __shared__ unsigned short Bs0[128 * 32];  // 8 KB
  __shared__ unsigned short Bs1[128 * 32];  // 8 KB

  const int tid  = threadIdx.x;
  const int lane = tid & 63;
  const int wave = tid >> 6;                // 4 waves, 2x2 over 128x128
  const int wm   = wave >> 1;
  const int wn   = wave & 1;
  const size_t rowA0 = (size_t)blockIdx.y * 128;
  const int    colB0 = blockIdx.x * 128;

  const int lrow = lane >> 2;               // 0..15 rows per 1KB issue
  const int lk8  = (lane & 3) * 8;          // bf16 element offset in K-slab

  const unsigned short* gA  = Xs + (rowA0 + lrow) * IDIM + lk8;
  const unsigned short* gB0 = Cb + ((size_t)(seg * ODIM + colB0 + lrow)) * IDIM + lk8;
  const unsigned short* gB1 = gB0 + (size_t)ODIM * IDIM;

  f32x4 acc0[4][4] = {};
  f32x4 acc1[4][4] = {};

  for (int kk = 0; kk < IDIM; kk += 32) {
    __syncthreads();                        // prior iter's LDS reads complete
#pragma unroll
    for (int t = 0; t < 2; t++) {
      int r0 = (wave * 2 + t) * 16;         // 16 rows (1024 B) per issue
      async_cp16(gA  + (size_t)r0 * IDIM + kk, &As[r0 * 32]);
      async_cp16(gB0 + (size_t)r0 * IDIM + kk, &Bs0[r0 * 32]);
      async_cp16(gB1 + (size_t)r0 * IDIM + kk, &Bs1[r0 * 32]);
    }
    __syncthreads();                        // staging visible (vmcnt drain at barrier)

    frag8 af[4], bfr[4];
#pragma unroll
    for (int mi = 0; mi < 4; mi++)
      af[mi] = *(const frag8*)&As[(wm * 64 + mi * 16 + (lane & 15)) * 32 + (lane >> 4) * 8];
#pragma unroll
    for (int ni = 0; ni < 4; ni++)
      bfr[ni] = *(const frag8*)&Bs0[(wn * 64 + ni * 16 + (lane & 15)) * 32 + (lane >> 4) * 8];
#pragma unroll
    for (int mi = 0; mi < 4; mi++)
#pragma unroll
      for (int ni = 0; ni < 4; ni++)
        acc0[mi][ni] = __builtin_amdgcn_mfma_f32_16x16x32_bf16(af[mi], bfr[ni], acc0[mi][ni], 0, 0, 0);
#pragma unroll
    for (int ni = 0; ni < 4; ni++)
      bfr[ni] = *(const frag8*)&Bs1[(wn * 64 + ni * 16 + (lane & 15)) * 32 + (lane >> 4) * 8];
#pragma unroll
    for (int mi = 0; mi < 4; mi++)
#pragma unroll
      for (int ni = 0; ni < 4; ni++)
        acc1[mi][ni] = __builtin_amdgcn_mfma_f32_16x16x32_bf16(af[mi], bfr[ni], acc1[mi][ni], 0, 0, 0);
  }

  // Epilogue: D col = lane&15, row = (lane>>4)*4 + reg  [m89/m91 verified]
  int   col[4]; float bv[4];
#pragma unroll
  for (int ni = 0; ni < 4; ni++) {
    col[ni] = colB0 + wn * 64 + ni * 16 + (lane & 15);
    bv[ni]  = bias[col[ni]];
  }
#pragma unroll
  for (int mi = 0; mi < 4; mi++) {
    int prow = (int)rowA0 + wm * 64 + mi * 16 + (lane >> 4) * 4;
#pragma unroll
    for (int r = 0; r < 4; r++) {
      int p = prow + r;
      int orow = row_idx[p];
      if ((unsigned)orow < (unsigned)B_ROWS) {
        float2 w = ws[p];
        float* o = out + (size_t)orow * ODIM;
#pragma unroll
        for (int ni = 0; ni < 4; ni++)
          o[col[ni]] = w.x * acc0[mi][ni][r] + w.y * acc1[mi][ni][r] + bv[ni];
      }
    }
  }
}

// ---------------- Fallback (ws too small): slow fp32, correct ----------------
__global__ void fallback_kernel(const float* __restrict__ x, const float* __restrict__ coeff,
                                const float* __restrict__ bias, float* __restrict__ out) {
  int b = blockIdx.x;
  int tid = threadIdx.x;
  __shared__ float xs[IDIM];
  __shared__ float ps[4];
  __shared__ float mw[2];
  __shared__ int   ms;
  float4 v = ((const float4*)(x + (size_t)b * IDIM))[tid];
  ((float4*)xs)[tid] = v;
  float s = v.x + v.y + v.z + v.w;
#pragma unroll
  for (int off = 32; off; off >>= 1) s += __shfl_down(s, off, 64);
  if ((tid & 63) == 0) ps[tid >> 6] = s;
  __syncthreads();
  if (tid == 0) {
    float m = (ps[0] + ps[1] + ps[2] + ps[3]) * (1.0f / (float)IDIM);
    int sI; float w0, w1;
    seg_weights(m, sI, w0, w1);
    mw[0] = w0; mw[1] = w1; ms = sI;
  }
  __syncthreads();
  float w0 = mw[0], w1 = mw[1]; int sI = ms;
  for (int o = tid; o < ODIM; o += 256) {
    const float* c0 = coeff + ((size_t)sI * ODIM + o) * IDIM;
    const float* c1 = c0 + (size_t)ODIM * IDIM;
    float a0 = 0.f, a1 = 0.f;
    for (int i = 0; i < IDIM; i++) { a0 += xs[i] * c0[i]; a1 += xs[i] * c1[i]; }
    out[(size_t)b * ODIM + o] = w0 * a0 + w1 * a1 + bias[o];
  }
}

extern "C" void kernel_launch(void* const* d_in, const int* in_sizes, int n_in,
                              void* d_out, int out_size, void* d_ws, size_t ws_size,
                              hipStream_t stream) {
  const float* x     = (const float*)d_in[0];
  const float* coeff = (const float*)d_in[1];
  const float* bias  = (const float*)d_in[2];
  float* out = (float*)d_out;

  // Workspace layout (16B-aligned chunks)
  size_t szXs = (size_t)MPAD_MAX * IDIM * sizeof(unsigned short);     // 35,913,728
  size_t szCb = (size_t)NGRID * ODIM * IDIM * sizeof(unsigned short); // 18,874,368
  size_t o0 = 0;
  unsigned short* Xs = (unsigned short*)((char*)d_ws + o0); o0 += szXs;
  unsigned short* Cb = (unsigned short*)((char*)d_ws + o0); o0 += szCb;
  float2* ws = (float2*)((char*)d_ws + o0); o0 += (size_t)MPAD_MAX * 8;
  float* w0a = (float*)((char*)d_ws + o0); o0 += (size_t)B_ROWS * 4;
  float* w1a = (float*)((char*)d_ws + o0); o0 += (size_t)B_ROWS * 4;
  int* sidx  = (int*)((char*)d_ws + o0);   o0 += (size_t)B_ROWS * 4;
  int* rank  = (int*)((char*)d_ws + o0);   o0 += (size_t)B_ROWS * 4;
  int* row_idx = (int*)((char*)d_ws + o0); o0 += (size_t)MPAD_MAX * 4;
  int* bucket_cnt = (int*)((char*)d_ws + o0); o0 += 256;
  int* bucket_off = (int*)((char*)d_ws + o0); o0 += 256;
  int* tile_seg   = (int*)((char*)d_ws + o0); o0 += 1024;

  if (ws_size < o0) {
    // Emergency slow path: no workspace required.
    fallback_kernel<<<B_ROWS, 256, 0, stream>>>(x, coeff, bias, out);
    return;
  }

  zero_meta<<<1, 64, 0, stream>>>(bucket_cnt);
  row_stats<<<RS_BLOCKS, 256, 0, stream>>>(x, w0a, w1a, sidx, rank, bucket_cnt);
  plan_kernel<<<1, 256, 0, stream>>>(bucket_cnt, bucket_off, tile_seg, row_idx);
  build_a<<<B_ROWS / BA_ROWS, 256, 0, stream>>>(x, w0a, w1a, sidx, rank, bucket_off, Xs, ws, row_idx);
  int n4 = NGRID * ODIM * IDIM / 4;
  cvt_coeff<<<(n4 + 255) / 256, 256, 0, stream>>>(coeff, Cb, n4);
  kan_gemm<<<dim3(ODIM / 128, MT_MAX), 256, 0, stream>>>(Xs, Cb, row_idx, tile_seg, ws, bias, out);
}

// Round 4
// 271.452 us; speedup vs baseline: 1.7816x; 1.0270x over previous
//
#include <hip/hip_runtime.h>
#include <math.h>

// Problem constants
#define B_ROWS 16384      // 8*2048 batch rows
#define IDIM   1024
#define ODIM   1024
#define NGRID  9          // NUM_SEGMENTS + 1
#define MT_MAX 137        // max padded M-tiles: ceil((16384 + 9*127)/128)
#define MPAD_MAX (MT_MAX*128)

#define RS_BLOCKS 1024
#define RS_ROWS   (B_ROWS / RS_BLOCKS)   // 16 rows per block

typedef __attribute__((ext_vector_type(8))) short frag8;   // 8 x bf16 (4 VGPRs)
typedef __attribute__((ext_vector_type(4))) float f32x4;   // MFMA accumulator

typedef __attribute__((address_space(1))) void gvoid;
typedef __attribute__((address_space(3))) void lvoid;

__device__ __forceinline__ void async_cp16(const void* g, void* l) {
  // 16B/lane global->LDS DMA; LDS dest = wave-uniform base + lane*16
  __builtin_amdgcn_global_load_lds((gvoid*)(void*)g, (lvoid*)l, 16, 0, 0);
}

__device__ __forceinline__ unsigned short f2bf(float f) {
  union { float f; unsigned u; } v; v.f = f;
  unsigned u = v.u;
  u += 0x7fffu + ((u >> 16) & 1u);      // round-to-nearest-even
  return (unsigned short)(u >> 16);
}

// Per-row hat weights: at most 2 nonzero, at segments {s, s+1}
__device__ __forceinline__ void seg_weights(float m, int& sI, float& w0, float& w1) {
  float wsum = 0.f, wg[NGRID];
#pragma unroll
  for (int g = 0; g < NGRID; g++) {
    float gv = -1.f + 0.25f * (float)g;
    float t = 1.f - fabsf(m - gv) * 4.f;   // 1/h = 4
    wg[g] = t > 0.f ? t : 0.f;
    wsum += wg[g];
  }
  int s = (int)floorf((m + 1.f) * 4.f);
  s = s < 0 ? 0 : (s > 7 ? 7 : s);
  float inv = 1.f / (wsum + 1e-8f);
  sI = s;
  w0 = wg[s] * inv;
  w1 = wg[s + 1] * inv;
}

// ---------------- Pass 0: zero bucket counters ----------------
__global__ void zero_meta(int* bucket_cnt) {
  if (threadIdx.x < NGRID) bucket_cnt[threadIdx.x] = 0;
}

// ---------------- Pass 1: row mean -> segment, weights, rank ----------------
// Two-level atomic aggregation: LDS histogram + local ranks, then <=9 global
// atomics per block. 1024 blocks (4/CU) for load-latency hiding.
__global__ void row_stats(const float* __restrict__ x, float* __restrict__ w0a,
                          float* __restrict__ w1a, int* __restrict__ sidx,
                          int* __restrict__ rank, int* __restrict__ bucket_cnt) {
  __shared__ int lcnt[NGRID];
  __shared__ int base[NGRID];
  __shared__ int lrank[RS_ROWS];
  __shared__ int lseg[RS_ROWS];
  const int tid  = threadIdx.x;          // 256 threads, 4 waves
  const int lane = tid & 63;
  const int wave = tid >> 6;
  if (tid < NGRID) lcnt[tid] = 0;
  __syncthreads();
  const int row0 = blockIdx.x * RS_ROWS;
#pragma unroll
  for (int it = 0; it < RS_ROWS / 4; ++it) {
    int r = it * 4 + wave;               // one wave per row
    int b = row0 + r;
    const float4* xr = (const float4*)(x + (size_t)b * IDIM);
    float s = 0.f;
#pragma unroll
    for (int j = 0; j < 4; j++) {        // 4 independent 16B loads/lane
      float4 v = xr[lane + j * 64];
      s += v.x + v.y + v.z + v.w;
    }
#pragma unroll
    for (int off = 32; off; off >>= 1) s += __shfl_down(s, off, 64);
    if (lane == 0) {
      float m = s * (1.0f / (float)IDIM);
      int sI; float w0, w1;
      seg_weights(m, sI, w0, w1);
      w0a[b] = w0; w1a[b] = w1; sidx[b] = sI;
      lseg[r] = sI;
      lrank[r] = atomicAdd(&lcnt[sI], 1);   // LDS atomic: cheap
    }
  }
  __syncthreads();
  if (tid < NGRID) base[tid] = lcnt[tid] ? atomicAdd(&bucket_cnt[tid], lcnt[tid]) : 0;
  __syncthreads();
  if (tid < RS_ROWS) rank[row0 + tid] = base[lseg[tid]] + lrank[tid];
}

// ---------------- Pass 2: build bf16 sorted X + weights, AND coeff->bf16 ----------------
// Bucket offsets computed locally from bucket_cnt (no plan kernel needed).
#define BA_ROWS   8
#define BA_BLOCKS (B_ROWS / BA_ROWS)     // 2048
#define CV_BLOCKS (NGRID * ODIM * IDIM / 4 / 256)  // 9216
__global__ void build_and_cvt(const float* __restrict__ x, const float* __restrict__ coeff,
                              const float* __restrict__ w0a, const float* __restrict__ w1a,
                              const int* __restrict__ sidx, const int* __restrict__ rank,
                              const int* __restrict__ bucket_cnt,
                              unsigned short* __restrict__ Xs, float2* __restrict__ ws,
                              int* __restrict__ row_idx, unsigned short* __restrict__ Cb) {
  const int tid = threadIdx.x;            // 256 threads
  if (blockIdx.x >= BA_BLOCKS) {
    // coeff fp32 -> bf16 part
    int i = (blockIdx.x - BA_BLOCKS) * 256 + tid;
    float4 v = ((const float4*)coeff)[i];
    ushort4 o;
    o.x = f2bf(v.x); o.y = f2bf(v.y); o.z = f2bf(v.z); o.w = f2bf(v.w);
    ((ushort4*)Cb)[i] = o;
    return;
  }
  __shared__ int soffs[NGRID];
  if (tid == 0) {
    int off = 0;
#pragma unroll
    for (int g = 0; g < NGRID; g++) { soffs[g] = off; off += ((bucket_cnt[g] + 127) >> 7) << 7; }
  }
  __syncthreads();
  const int b0 = blockIdx.x * BA_ROWS;
#pragma unroll
  for (int r = 0; r < BA_ROWS; r++) {
    int b = b0 + r;
    int s = sidx[b];
    int p = soffs[s] + rank[b];
    if (tid == 0) { row_idx[p] = b; ws[p] = make_float2(w0a[b], w1a[b]); }
    float4 v = ((const float4*)(x + (size_t)b * IDIM))[tid];
    ushort4 u;
    u.x = f2bf(v.x); u.y = f2bf(v.y); u.z = f2bf(v.z); u.w = f2bf(v.w);
    *(ushort4*)(Xs + (size_t)p * IDIM + tid * 4) = u;
  }
}

// ---------------- Pass 3: MFMA GEMM, dual-accumulator, BK=64 ----------------
// acc0 = Xs_tile @ coeff[seg]^T, acc1 = Xs_tile @ coeff[seg+1]^T  (K=1024)
// out[row] = w0[row]*acc0 + w1[row]*acc1 + bias.
// BK=64 staged as two 32-K sub-slabs per barrier pair: 16 drains (was 32).
// Grid: (8 n-tiles FAST, m-tiles) -> 8 blocks sharing an A M-tile go to 8 XCDs.
__global__ void __launch_bounds__(256, 2)
kan_gemm(const unsigned short* __restrict__ Xs,
         const unsigned short* __restrict__ Cb,
         const int* __restrict__ row_idx,
         const int* __restrict__ bucket_cnt,
         const float2* __restrict__ ws,
         const float* __restrict__ bias,
         float* __restrict__ out) {
  // Derive this m-tile's segment + valid-row bound from the 9 counters.
  const int mt = blockIdx.y;
  int seg = -1, pend = 0;
  {
    int off = 0;
#pragma unroll
    for (int g = 0; g < NGRID; g++) {
      int c  = bucket_cnt[g];
      int nt = (c + 127) >> 7;
      int t0 = off >> 7;
      if (mt >= t0 && mt < t0 + nt) { seg = g; pend = off + c; }
      off += nt << 7;
    }
  }
  if (seg < 0) return;                      // uniform over block: barrier-safe

  __shared__ unsigned short As[2][128 * 32];   // 16 KB
  __shared__ unsigned short Bs0[2][128 * 32];  // 16 KB
  __shared__ unsigned short Bs1[2][128 * 32];  // 16 KB

  const int tid  = threadIdx.x;
  const int lane = tid & 63;
  const int wave = tid >> 6;                // 4 waves, 2x2 over 128x128
  const int wm   = wave >> 1;
  const int wn   = wave & 1;
  const size_t rowA0 = (size_t)mt * 128;
  const int    colB0 = blockIdx.x * 128;

  const int lrow = lane >> 2;               // 0..15 rows per 1KB issue
  const int lk8  = (lane & 3) * 8;          // bf16 element offset in K-slab

  const unsigned short* gA  = Xs + (rowA0 + lrow) * IDIM + lk8;
  const unsigned short* gB0 = Cb + ((size_t)(seg * ODIM + colB0 + lrow)) * IDIM + lk8;
  const unsigned short* gB1 = gB0 + (size_t)ODIM * IDIM;

  f32x4 acc0[4][4] = {};
  f32x4 acc1[4][4] = {};

  for (int kk = 0; kk < IDIM; kk += 64) {
    __syncthreads();                        // prior iter's LDS reads complete
#pragma unroll
    for (int h = 0; h < 2; h++) {
#pragma unroll
      for (int t = 0; t < 2; t++) {
        int r0 = (wave * 2 + t) * 16;       // 16 rows (1024 B) per issue
        int ko = kk + h * 32;
        async_cp16(gA  + (size_t)r0 * IDIM + ko, &As[h][r0 * 32]);
        async_cp16(gB0 + (size_t)r0 * IDIM + ko, &Bs0[h][r0 * 32]);
        async_cp16(gB1 + (size_t)r0 * IDIM + ko, &Bs1[h][r0 * 32]);
      }
    }
    __syncthreads();                        // staging visible (vmcnt drain at barrier)

#pragma unroll
    for (int h = 0; h < 2; h++) {
      frag8 af[4], bfr[4];
#pragma unroll
      for (int mi = 0; mi < 4; mi++)
        af[mi] = *(const frag8*)&As[h][(wm * 64 + mi * 16 + (lane & 15)) * 32 + (lane >> 4) * 8];
#pragma unroll
      for (int ni = 0; ni < 4; ni++)
        bfr[ni] = *(const frag8*)&Bs0[h][(wn * 64 + ni * 16 + (lane & 15)) * 32 + (lane >> 4) * 8];
#pragma unroll
      for (int mi = 0; mi < 4; mi++)
#pragma unroll
        for (int ni = 0; ni < 4; ni++)
          acc0[mi][ni] = __builtin_amdgcn_mfma_f32_16x16x32_bf16(af[mi], bfr[ni], acc0[mi][ni], 0, 0, 0);
#pragma unroll
      for (int ni = 0; ni < 4; ni++)
        bfr[ni] = *(const frag8*)&Bs1[h][(wn * 64 + ni * 16 + (lane & 15)) * 32 + (lane >> 4) * 8];
#pragma unroll
      for (int mi = 0; mi < 4; mi++)
#pragma unroll
        for (int ni = 0; ni < 4; ni++)
          acc1[mi][ni] = __builtin_amdgcn_mfma_f32_16x16x32_bf16(af[mi], bfr[ni], acc1[mi][ni], 0, 0, 0);
    }
  }

  // Epilogue: D col = lane&15, row = (lane>>4)*4 + reg  [m89/m91 verified]
  int   col[4]; float bv[4];
#pragma unroll
  for (int ni = 0; ni < 4; ni++) {
    col[ni] = colB0 + wn * 64 + ni * 16 + (lane & 15);
    bv[ni]  = bias[col[ni]];
  }
#pragma unroll
  for (int mi = 0; mi < 4; mi++) {
    int prow = (int)rowA0 + wm * 64 + mi * 16 + (lane >> 4) * 4;
#pragma unroll
    for (int r = 0; r < 4; r++) {
      int p = prow + r;
      if (p < pend) {                       // in-bucket (non-padding) row
        int orow = row_idx[p];
        float2 w = ws[p];
        float* o = out + (size_t)orow * ODIM;
#pragma unroll
        for (int ni = 0; ni < 4; ni++)
          o[col[ni]] = w.x * acc0[mi][ni][r] + w.y * acc1[mi][ni][r] + bv[ni];
      }
    }
  }
}

// ---------------- Fallback (ws too small): slow fp32, correct ----------------
__global__ void fallback_kernel(const float* __restrict__ x, const float* __restrict__ coeff,
                                const float* __restrict__ bias, float* __restrict__ out) {
  int b = blockIdx.x;
  int tid = threadIdx.x;
  __shared__ float xs[IDIM];
  __shared__ float ps[4];
  __shared__ float mw[2];
  __shared__ int   ms;
  float4 v = ((const float4*)(x + (size_t)b * IDIM))[tid];
  ((float4*)xs)[tid] = v;
  float s = v.x + v.y + v.z + v.w;
#pragma unroll
  for (int off = 32; off; off >>= 1) s += __shfl_down(s, off, 64);
  if ((tid & 63) == 0) ps[tid >> 6] = s;
  __syncthreads();
  if (tid == 0) {
    float m = (ps[0] + ps[1] + ps[2] + ps[3]) * (1.0f / (float)IDIM);
    int sI; float w0, w1;
    seg_weights(m, sI, w0, w1);
    mw[0] = w0; mw[1] = w1; ms = sI;
  }
  __syncthreads();
  float w0 = mw[0], w1 = mw[1]; int sI = ms;
  for (int o = tid; o < ODIM; o += 256) {
    const float* c0 = coeff + ((size_t)sI * ODIM + o) * IDIM;
    const float* c1 = c0 + (size_t)ODIM * IDIM;
    float a0 = 0.f, a1 = 0.f;
    for (int i = 0; i < IDIM; i++) { a0 += xs[i] * c0[i]; a1 += xs[i] * c1[i]; }
    out[(size_t)b * ODIM + o] = w0 * a0 + w1 * a1 + bias[o];
  }
}

extern "C" void kernel_launch(void* const* d_in, const int* in_sizes, int n_in,
                              void* d_out, int out_size, void* d_ws, size_t ws_size,
                              hipStream_t stream) {
  const float* x     = (const float*)d_in[0];
  const float* coeff = (const float*)d_in[1];
  const float* bias  = (const float*)d_in[2];
  float* out = (float*)d_out;

  // Workspace layout (16B-aligned chunks)
  size_t szXs = (size_t)MPAD_MAX * IDIM * sizeof(unsigned short);     // 35,913,728
  size_t szCb = (size_t)NGRID * ODIM * IDIM * sizeof(unsigned short); // 18,874,368
  size_t o0 = 0;
  unsigned short* Xs = (unsigned short*)((char*)d_ws + o0); o0 += szXs;
  unsigned short* Cb = (unsigned short*)((char*)d_ws + o0); o0 += szCb;
  float2* ws = (float2*)((char*)d_ws + o0); o0 += (size_t)MPAD_MAX * 8;
  float* w0a = (float*)((char*)d_ws + o0); o0 += (size_t)B_ROWS * 4;
  float* w1a = (float*)((char*)d_ws + o0); o0 += (size_t)B_ROWS * 4;
  int* sidx  = (int*)((char*)d_ws + o0);   o0 += (size_t)B_ROWS * 4;
  int* rank  = (int*)((char*)d_ws + o0);   o0 += (size_t)B_ROWS * 4;
  int* row_idx = (int*)((char*)d_ws + o0); o0 += (size_t)MPAD_MAX * 4;
  int* bucket_cnt = (int*)((char*)d_ws + o0); o0 += 256;

  if (ws_size < o0) {
    // Emergency slow path: no workspace required.
    fallback_kernel<<<B_ROWS, 256, 0, stream>>>(x, coeff, bias, out);
    return;
  }

  zero_meta<<<1, 64, 0, stream>>>(bucket_cnt);
  row_stats<<<RS_BLOCKS, 256, 0, stream>>>(x, w0a, w1a, sidx, rank, bucket_cnt);
  build_and_cvt<<<BA_BLOCKS + CV_BLOCKS, 256, 0, stream>>>(x, coeff, w0a, w1a, sidx, rank,
                                                           bucket_cnt, Xs, ws, row_idx, Cb);
  kan_gemm<<<dim3(ODIM / 128, MT_MAX), 256, 0, stream>>>(Xs, Cb, row_idx, bucket_cnt, ws, bias, out);
}

// Round 5
// 247.085 us; speedup vs baseline: 1.9573x; 1.0986x over previous
//
#include <hip/hip_runtime.h>
#include <math.h>

// Problem constants
#define B_ROWS 16384      // 8*2048 batch rows
#define IDIM   1024
#define ODIM   1024
#define NGRID  9          // NUM_SEGMENTS + 1

#define RS_BLOCKS 1024
#define RS_ROWS   (B_ROWS / RS_BLOCKS)   // 16 rows per block

// GEMM grid: 18 groups x 64 = 1152 blocks; swizzle gives m-tile's 8 n-blocks
// the same (id mod 8) class within a 64-id window -> same XCD (round-robin).
#define GEMM_GROUPS 18
#define GEMM_BLOCKS (GEMM_GROUPS * 64)

typedef __attribute__((ext_vector_type(8))) short frag8;   // 8 x bf16 (4 VGPRs)
typedef __attribute__((ext_vector_type(4))) float f32x4;   // MFMA accumulator

typedef __attribute__((address_space(1))) void gvoid;
typedef __attribute__((address_space(3))) void lvoid;

__device__ __forceinline__ void async_cp16(const void* g, void* l) {
  // 16B/lane global->LDS DMA; LDS dest = wave-uniform base + lane*16.
  // Global side is a normal per-lane VMEM address (gather OK).
  __builtin_amdgcn_global_load_lds((gvoid*)(void*)g, (lvoid*)l, 16, 0, 0);
}

__device__ __forceinline__ unsigned short f2bf(float f) {
  union { float f; unsigned u; } v; v.f = f;
  unsigned u = v.u;
  u += 0x7fffu + ((u >> 16) & 1u);      // round-to-nearest-even
  return (unsigned short)(u >> 16);
}

// Per-row hat weights: at most 2 nonzero, at segments {s, s+1}
__device__ __forceinline__ void seg_weights(float m, int& sI, float& w0, float& w1) {
  float wsum = 0.f, wg[NGRID];
#pragma unroll
  for (int g = 0; g < NGRID; g++) {
    float gv = -1.f + 0.25f * (float)g;
    float t = 1.f - fabsf(m - gv) * 4.f;   // 1/h = 4
    wg[g] = t > 0.f ? t : 0.f;
    wsum += wg[g];
  }
  int s = (int)floorf((m + 1.f) * 4.f);
  s = s < 0 ? 0 : (s > 7 ? 7 : s);
  float inv = 1.f / (wsum + 1e-8f);
  sI = s;
  w0 = wg[s] * inv;
  w1 = wg[s + 1] * inv;
}

// ---------------- Pass 0: zero bucket counters ----------------
__global__ void zero_meta(int* bucket_cnt) {
  if (threadIdx.x < NGRID) bucket_cnt[threadIdx.x] = 0;
}

// ---------------- Pass 1 (fused): mean/weights/segment + bf16 cvt + seg lists --
// Each wave handles one row: data stays in registers, so the bf16 copy is
// written with NO re-read. Two-level atomic aggregation for ranks.
__global__ void row_stats_fused(const float* __restrict__ x,
                                unsigned short* __restrict__ Xb,
                                float2* __restrict__ ws2,
                                int* __restrict__ seg_rows,
                                int* __restrict__ bucket_cnt) {
  __shared__ int lcnt[NGRID];
  __shared__ int base[NGRID];
  __shared__ int lrank[RS_ROWS];
  __shared__ int lseg[RS_ROWS];
  const int tid  = threadIdx.x;          // 256 threads, 4 waves
  const int lane = tid & 63;
  const int wave = tid >> 6;
  if (tid < NGRID) lcnt[tid] = 0;
  __syncthreads();
  const int row0 = blockIdx.x * RS_ROWS;
#pragma unroll
  for (int it = 0; it < RS_ROWS / 4; ++it) {
    int r = it * 4 + wave;               // one wave per row
    int b = row0 + r;
    const float4* xr = (const float4*)(x + (size_t)b * IDIM);
    ushort4* xw = (ushort4*)(Xb + (size_t)b * IDIM);
    float4 v[4];
    float s = 0.f;
#pragma unroll
    for (int j = 0; j < 4; j++) {        // 4 independent 16B loads/lane
      v[j] = xr[lane + j * 64];
      s += v[j].x + v[j].y + v[j].z + v[j].w;
    }
#pragma unroll
    for (int j = 0; j < 4; j++) {        // bf16 copy straight from registers
      ushort4 u;
      u.x = f2bf(v[j].x); u.y = f2bf(v[j].y); u.z = f2bf(v[j].z); u.w = f2bf(v[j].w);
      xw[lane + j * 64] = u;
    }
#pragma unroll
    for (int off = 32; off; off >>= 1) s += __shfl_down(s, off, 64);
    if (lane == 0) {
      float m = s * (1.0f / (float)IDIM);
      int sI; float w0, w1;
      seg_weights(m, sI, w0, w1);
      ws2[b] = make_float2(w0, w1);
      lseg[r] = sI;
      lrank[r] = atomicAdd(&lcnt[sI], 1);   // LDS atomic: cheap
    }
  }
  __syncthreads();
  if (tid < NGRID) base[tid] = lcnt[tid] ? atomicAdd(&bucket_cnt[tid], lcnt[tid]) : 0;
  __syncthreads();
  if (tid < RS_ROWS)
    seg_rows[lseg[tid] * B_ROWS + base[lseg[tid]] + lrank[tid]] = row0 + tid;
}

// ---------------- Pass 2: coeff fp32 -> bf16, only planes actually needed ----
// Plane h is needed iff some non-empty bucket g has h in {g, g+1}.
#define CV_BLKS_PER_PLANE (ODIM * IDIM / 4 / 256)   // 1024
__global__ void cvt_coeff(const float* __restrict__ c, unsigned short* __restrict__ cb,
                          const int* __restrict__ bucket_cnt) {
  const int g  = blockIdx.x >> 10;            // plane 0..8
  const int cI = blockIdx.x & 1023;
  bool need = bucket_cnt[g] > 0;
  if (!need && g > 0) need = bucket_cnt[g - 1] > 0;
  if (!need) return;
  int i = (g * CV_BLKS_PER_PLANE + cI) * 256 + threadIdx.x;
  float4 v = ((const float4*)c)[i];
  ushort4 o;
  o.x = f2bf(v.x); o.y = f2bf(v.y); o.z = f2bf(v.z); o.w = f2bf(v.w);
  ((ushort4*)cb)[i] = o;
}

// ---------------- Pass 3: MFMA GEMM, dual-accumulator, BK=64, gather-A -------
// acc0 = X[rows] @ coeff[seg]^T, acc1 = X[rows] @ coeff[seg+1]^T  (K=1024)
// out[row] = w0[row]*acc0 + w1[row]*acc1 + bias.  Rows gathered per-lane from
// unsorted bf16 Xb via seg_rows (no sorted copy materialized).
__global__ void __launch_bounds__(256, 2)
kan_gemm(const unsigned short* __restrict__ Xb,
         const unsigned short* __restrict__ Cb,
         const int* __restrict__ seg_rows,
         const int* __restrict__ bucket_cnt,
         const float2* __restrict__ ws2,
         const float* __restrict__ bias,
         float* __restrict__ out) {
  // XCD swizzle: sub&7 -> m-tile class (same XCD), sub>>3 -> n-tile.
  const int sub = blockIdx.x & 63;
  const int mt  = (blockIdx.x >> 6) * 8 + (sub & 7);
  const int nt  = sub >> 3;

  // Map m-tile -> (segment, local tile, bucket count) from the 9 counters.
  int seg = -1, lt = 0, cnt = 0;
  {
    int t0 = 0;
#pragma unroll
    for (int g = 0; g < NGRID; g++) {
      int c   = bucket_cnt[g];
      int ntg = (c + 127) >> 7;
      if (mt >= t0 && mt < t0 + ntg) { seg = g; lt = mt - t0; cnt = c; }
      t0 += ntg;
    }
  }
  if (seg < 0) return;                      // uniform over block: barrier-safe
  const int rlim = cnt - lt * 128;          // valid rows in this tile (1..128)
  const int* rows = seg_rows + seg * B_ROWS + lt * 128;

  __shared__ unsigned short As[2][128 * 32];   // 16 KB
  __shared__ unsigned short Bs0[2][128 * 32];  // 16 KB
  __shared__ unsigned short Bs1[2][128 * 32];  // 16 KB

  const int tid  = threadIdx.x;
  const int lane = tid & 63;
  const int wave = tid >> 6;                // 4 waves, 2x2 over 128x128
  const int wm   = wave >> 1;
  const int wn   = wave & 1;
  const int colB0 = nt * 128;

  const int lrow = lane >> 2;               // 0..15 rows per 1KB issue
  const int lk8  = (lane & 3) * 8;          // bf16 element offset in K-slab

  // Per-lane A-row ids for this wave's two 16-row staging groups (constant
  // over the K-loop). Clamp padding lanes to a valid row (masked at epilogue).
  int rid[2];
#pragma unroll
  for (int t = 0; t < 2; t++) {
    int idx = (wave * 2 + t) * 16 + lrow;
    rid[t] = rows[idx < rlim ? idx : rlim - 1];
  }

  const unsigned short* gB0 = Cb + ((size_t)(seg * ODIM + colB0 + lrow)) * IDIM + lk8;
  const unsigned short* gB1 = gB0 + (size_t)ODIM * IDIM;

  f32x4 acc0[4][4] = {};
  f32x4 acc1[4][4] = {};

  for (int kk = 0; kk < IDIM; kk += 64) {
    __syncthreads();                        // prior iter's LDS reads complete
#pragma unroll
    for (int h = 0; h < 2; h++) {
      int ko = kk + h * 32;
#pragma unroll
      for (int t = 0; t < 2; t++) {
        int r0 = (wave * 2 + t) * 16;       // 16 rows (1024 B) per issue
        async_cp16(Xb + (size_t)rid[t] * IDIM + ko + lk8, &As[h][r0 * 32]);
        async_cp16(gB0 + (size_t)r0 * IDIM + ko, &Bs0[h][r0 * 32]);
        async_cp16(gB1 + (size_t)r0 * IDIM + ko, &Bs1[h][r0 * 32]);
      }
    }
    __syncthreads();                        // staging visible (vmcnt drain at barrier)

#pragma unroll
    for (int h = 0; h < 2; h++) {
      frag8 af[4], bfr[4];
#pragma unroll
      for (int mi = 0; mi < 4; mi++)
        af[mi] = *(const frag8*)&As[h][(wm * 64 + mi * 16 + (lane & 15)) * 32 + (lane >> 4) * 8];
#pragma unroll
      for (int ni = 0; ni < 4; ni++)
        bfr[ni] = *(const frag8*)&Bs0[h][(wn * 64 + ni * 16 + (lane & 15)) * 32 + (lane >> 4) * 8];
#pragma unroll
      for (int mi = 0; mi < 4; mi++)
#pragma unroll
        for (int ni = 0; ni < 4; ni++)
          acc0[mi][ni] = __builtin_amdgcn_mfma_f32_16x16x32_bf16(af[mi], bfr[ni], acc0[mi][ni], 0, 0, 0);
#pragma unroll
      for (int ni = 0; ni < 4; ni++)
        bfr[ni] = *(const frag8*)&Bs1[h][(wn * 64 + ni * 16 + (lane & 15)) * 32 + (lane >> 4) * 8];
#pragma unroll
      for (int mi = 0; mi < 4; mi++)
#pragma unroll
        for (int ni = 0; ni < 4; ni++)
          acc1[mi][ni] = __builtin_amdgcn_mfma_f32_16x16x32_bf16(af[mi], bfr[ni], acc1[mi][ni], 0, 0, 0);
    }
  }

  // Epilogue: D col = lane&15, row = (lane>>4)*4 + reg  [m89/m91 verified]
  int   col[4]; float bv[4];
#pragma unroll
  for (int ni = 0; ni < 4; ni++) {
    col[ni] = colB0 + wn * 64 + ni * 16 + (lane & 15);
    bv[ni]  = bias[col[ni]];
  }
#pragma unroll
  for (int mi = 0; mi < 4; mi++) {
    int irow = wm * 64 + mi * 16 + (lane >> 4) * 4;
#pragma unroll
    for (int r = 0; r < 4; r++) {
      int idx = irow + r;
      if (idx < rlim) {                     // non-padding row
        int orow = rows[idx];
        float2 w = ws2[orow];
        float* o = out + (size_t)orow * ODIM;
#pragma unroll
        for (int ni = 0; ni < 4; ni++)
          o[col[ni]] = w.x * acc0[mi][ni][r] + w.y * acc1[mi][ni][r] + bv[ni];
      }
    }
  }
}

// ---------------- Fallback (ws too small): slow fp32, correct ----------------
__global__ void fallback_kernel(const float* __restrict__ x, const float* __restrict__ coeff,
                                const float* __restrict__ bias, float* __restrict__ out) {
  int b = blockIdx.x;
  int tid = threadIdx.x;
  __shared__ float xs[IDIM];
  __shared__ float ps[4];
  __shared__ float mw[2];
  __shared__ int   ms;
  float4 v = ((const float4*)(x + (size_t)b * IDIM))[tid];
  ((float4*)xs)[tid] = v;
  float s = v.x + v.y + v.z + v.w;
#pragma unroll
  for (int off = 32; off; off >>= 1) s += __shfl_down(s, off, 64);
  if ((tid & 63) == 0) ps[tid >> 6] = s;
  __syncthreads();
  if (tid == 0) {
    float m = (ps[0] + ps[1] + ps[2] + ps[3]) * (1.0f / (float)IDIM);
    int sI; float w0, w1;
    seg_weights(m, sI, w0, w1);
    mw[0] = w0; mw[1] = w1; ms = sI;
  }
  __syncthreads();
  float w0 = mw[0], w1 = mw[1]; int sI = ms;
  for (int o = tid; o < ODIM; o += 256) {
    const float* c0 = coeff + ((size_t)sI * ODIM + o) * IDIM;
    const float* c1 = c0 + (size_t)ODIM * IDIM;
    float a0 = 0.f, a1 = 0.f;
    for (int i = 0; i < IDIM; i++) { a0 += xs[i] * c0[i]; a1 += xs[i] * c1[i]; }
    out[(size_t)b * ODIM + o] = w0 * a0 + w1 * a1 + bias[o];
  }
}

extern "C" void kernel_launch(void* const* d_in, const int* in_sizes, int n_in,
                              void* d_out, int out_size, void* d_ws, size_t ws_size,
                              hipStream_t stream) {
  const float* x     = (const float*)d_in[0];
  const float* coeff = (const float*)d_in[1];
  const float* bias  = (const float*)d_in[2];
  float* out = (float*)d_out;

  // Workspace layout (16B-aligned chunks)
  size_t szXb = (size_t)B_ROWS * IDIM * sizeof(unsigned short);       // 33,554,432
  size_t szCb = (size_t)NGRID * ODIM * IDIM * sizeof(unsigned short); // 18,874,368
  size_t o0 = 0;
  unsigned short* Xb = (unsigned short*)((char*)d_ws + o0); o0 += szXb;
  unsigned short* Cb = (unsigned short*)((char*)d_ws + o0); o0 += szCb;
  float2* ws2 = (float2*)((char*)d_ws + o0); o0 += (size_t)B_ROWS * 8;
  int* seg_rows = (int*)((char*)d_ws + o0); o0 += (size_t)NGRID * B_ROWS * 4;
  int* bucket_cnt = (int*)((char*)d_ws + o0); o0 += 256;

  if (ws_size < o0) {
    // Emergency slow path: no workspace required.
    fallback_kernel<<<B_ROWS, 256, 0, stream>>>(x, coeff, bias, out);
    return;
  }

  zero_meta<<<1, 64, 0, stream>>>(bucket_cnt);
  row_stats_fused<<<RS_BLOCKS, 256, 0, stream>>>(x, Xb, ws2, seg_rows, bucket_cnt);
  cvt_coeff<<<NGRID * CV_BLKS_PER_PLANE, 256, 0, stream>>>(coeff, Cb, bucket_cnt);
  kan_gemm<<<GEMM_BLOCKS, 256, 0, stream>>>(Xb, Cb, seg_rows, bucket_cnt, ws2, bias, out);
}

// Round 6
// 234.444 us; speedup vs baseline: 2.0628x; 1.0539x over previous
//
#include <hip/hip_runtime.h>
#include <math.h>

// Problem constants
#define B_ROWS 16384      // 8*2048 batch rows
#define IDIM   1024
#define ODIM   1024
#define NGRID  9          // NUM_SEGMENTS + 1

#define RS_BLOCKS 1024
#define RS_ROWS   (B_ROWS / RS_BLOCKS)   // 16 rows per block

// GEMM grid: BM=128 BN=64 -> 16 n-tiles. 18 groups x 128 = 2304 blocks.
// Swizzle: within a 128-id window, (id&7) selects m-tile class -> the 16
// n-blocks of one m-tile share an XCD (round-robin dispatch) for A-tile L2 reuse.
#define GEMM_GROUPS 18
#define GEMM_BLOCKS (GEMM_GROUPS * 128)

typedef __attribute__((ext_vector_type(8))) short frag8;   // 8 x bf16 (4 VGPRs)
typedef __attribute__((ext_vector_type(4))) float f32x4;   // MFMA accumulator

typedef __attribute__((address_space(1))) void gvoid;
typedef __attribute__((address_space(3))) void lvoid;

__device__ __forceinline__ void async_cp16(const void* g, void* l) {
  // 16B/lane global->LDS DMA; LDS dest = wave-uniform base + lane*16.
  // Global side is a normal per-lane VMEM address (gather OK).
  __builtin_amdgcn_global_load_lds((gvoid*)(void*)g, (lvoid*)l, 16, 0, 0);
}

__device__ __forceinline__ unsigned short f2bf(float f) {
  union { float f; unsigned u; } v; v.f = f;
  unsigned u = v.u;
  u += 0x7fffu + ((u >> 16) & 1u);      // round-to-nearest-even
  return (unsigned short)(u >> 16);
}

// Per-row hat weights: at most 2 nonzero, at segments {s, s+1}
__device__ __forceinline__ void seg_weights(float m, int& sI, float& w0, float& w1) {
  float wsum = 0.f, wg[NGRID];
#pragma unroll
  for (int g = 0; g < NGRID; g++) {
    float gv = -1.f + 0.25f * (float)g;
    float t = 1.f - fabsf(m - gv) * 4.f;   // 1/h = 4
    wg[g] = t > 0.f ? t : 0.f;
    wsum += wg[g];
  }
  int s = (int)floorf((m + 1.f) * 4.f);
  s = s < 0 ? 0 : (s > 7 ? 7 : s);
  float inv = 1.f / (wsum + 1e-8f);
  sI = s;
  w0 = wg[s] * inv;
  w1 = wg[s + 1] * inv;
}

// ---------------- Pass 0: zero bucket counters ----------------
__global__ void zero_meta(int* bucket_cnt) {
  if (threadIdx.x < NGRID) bucket_cnt[threadIdx.x] = 0;
}

// ---------------- Pass 1 (fused): mean/weights/segment + bf16 cvt + seg lists --
// Each wave handles one row: data stays in registers, so the bf16 copy is
// written with NO re-read. Two-level atomic aggregation for ranks.
__global__ void row_stats_fused(const float* __restrict__ x,
                                unsigned short* __restrict__ Xb,
                                float2* __restrict__ ws2,
                                int* __restrict__ seg_rows,
                                int* __restrict__ bucket_cnt) {
  __shared__ int lcnt[NGRID];
  __shared__ int base[NGRID];
  __shared__ int lrank[RS_ROWS];
  __shared__ int lseg[RS_ROWS];
  const int tid  = threadIdx.x;          // 256 threads, 4 waves
  const int lane = tid & 63;
  const int wave = tid >> 6;
  if (tid < NGRID) lcnt[tid] = 0;
  __syncthreads();
  const int row0 = blockIdx.x * RS_ROWS;
#pragma unroll
  for (int it = 0; it < RS_ROWS / 4; ++it) {
    int r = it * 4 + wave;               // one wave per row
    int b = row0 + r;
    const float4* xr = (const float4*)(x + (size_t)b * IDIM);
    ushort4* xw = (ushort4*)(Xb + (size_t)b * IDIM);
    float4 v[4];
    float s = 0.f;
#pragma unroll
    for (int j = 0; j < 4; j++) {        // 4 independent 16B loads/lane
      v[j] = xr[lane + j * 64];
      s += v[j].x + v[j].y + v[j].z + v[j].w;
    }
#pragma unroll
    for (int j = 0; j < 4; j++) {        // bf16 copy straight from registers
      ushort4 u;
      u.x = f2bf(v[j].x); u.y = f2bf(v[j].y); u.z = f2bf(v[j].z); u.w = f2bf(v[j].w);
      xw[lane + j * 64] = u;
    }
#pragma unroll
    for (int off = 32; off; off >>= 1) s += __shfl_down(s, off, 64);
    if (lane == 0) {
      float m = s * (1.0f / (float)IDIM);
      int sI; float w0, w1;
      seg_weights(m, sI, w0, w1);
      ws2[b] = make_float2(w0, w1);
      lseg[r] = sI;
      lrank[r] = atomicAdd(&lcnt[sI], 1);   // LDS atomic: cheap
    }
  }
  __syncthreads();
  if (tid < NGRID) base[tid] = lcnt[tid] ? atomicAdd(&bucket_cnt[tid], lcnt[tid]) : 0;
  __syncthreads();
  if (tid < RS_ROWS)
    seg_rows[lseg[tid] * B_ROWS + base[lseg[tid]] + lrank[tid]] = row0 + tid;
}

// ---------------- Pass 2: coeff fp32 -> bf16, only planes actually needed ----
// Plane h is needed iff some non-empty bucket g has h in {g, g+1}.
#define CV_BLKS_PER_PLANE (ODIM * IDIM / 4 / 256)   // 1024
__global__ void cvt_coeff(const float* __restrict__ c, unsigned short* __restrict__ cb,
                          const int* __restrict__ bucket_cnt) {
  const int g  = blockIdx.x >> 10;            // plane 0..8
  const int cI = blockIdx.x & 1023;
  bool need = bucket_cnt[g] > 0;
  if (!need && g > 0) need = bucket_cnt[g - 1] > 0;
  if (!need) return;
  int i = (g * CV_BLKS_PER_PLANE + cI) * 256 + threadIdx.x;
  float4 v = ((const float4*)c)[i];
  ushort4 o;
  o.x = f2bf(v.x); o.y = f2bf(v.y); o.z = f2bf(v.z); o.w = f2bf(v.w);
  ((ushort4*)cb)[i] = o;
}

// ---------------- Pass 3: MFMA GEMM, dual-acc, BM=128 BN=64, BK=64, gather-A --
// acc0 = X[rows] @ coeff[seg]^T, acc1 = X[rows] @ coeff[seg+1]^T  (K=1024)
// out[row] = w0[row]*acc0 + w1[row]*acc1 + bias.  Rows gathered per-lane from
// unsorted bf16 Xb via seg_rows. BN=64 halves acc regs (64 vs 128) ->
// 3 waves/SIMD instead of 2: more overlap against the staging drain.
__global__ void __launch_bounds__(256, 3)
kan_gemm(const unsigned short* __restrict__ Xb,
         const unsigned short* __restrict__ Cb,
         const int* __restrict__ seg_rows,
         const int* __restrict__ bucket_cnt,
         const float2* __restrict__ ws2,
         const float* __restrict__ bias,
         float* __restrict__ out) {
  // XCD swizzle: sub&7 -> m-tile class (same XCD), sub>>3 -> n-tile (0..15).
  const int sub = blockIdx.x & 127;
  const int mt  = (blockIdx.x >> 7) * 8 + (sub & 7);
  const int nt  = sub >> 3;

  // Map m-tile -> (segment, local tile, bucket count) from the 9 counters.
  int seg = -1, lt = 0, cnt = 0;
  {
    int t0 = 0;
#pragma unroll
    for (int g = 0; g < NGRID; g++) {
      int c   = bucket_cnt[g];
      int ntg = (c + 127) >> 7;
      if (mt >= t0 && mt < t0 + ntg) { seg = g; lt = mt - t0; cnt = c; }
      t0 += ntg;
    }
  }
  if (seg < 0) return;                      // uniform over block: barrier-safe
  const int rlim = cnt - lt * 128;          // valid rows in this tile (1..128)
  const int* rows = seg_rows + seg * B_ROWS + lt * 128;

  __shared__ unsigned short As[2][128 * 32];   // 16 KB
  __shared__ unsigned short Bs0[2][64 * 32];   // 8 KB
  __shared__ unsigned short Bs1[2][64 * 32];   // 8 KB

  const int tid  = threadIdx.x;
  const int lane = tid & 63;
  const int wave = tid >> 6;                // 4 waves, 2x2 over 128x64
  const int wm   = wave >> 1;               // 0..1 -> 64-row half
  const int wn   = wave & 1;                // 0..1 -> 32-col half
  const int colB0 = nt * 64;

  const int lrow = lane >> 2;               // 0..15 rows per 1KB issue
  const int lk8  = (lane & 3) * 8;          // bf16 element offset in K-slab

  // Per-lane A-row ids for this wave's two 16-row staging groups (constant
  // over the K-loop). Clamp padding lanes to a valid row (masked at epilogue).
  int rid[2];
#pragma unroll
  for (int t = 0; t < 2; t++) {
    int idx = (wave * 2 + t) * 16 + lrow;
    rid[t] = rows[idx < rlim ? idx : rlim - 1];
  }

  // B staging: each wave loads one 16-row group of the 64-row B tiles.
  const unsigned short* gB0 = Cb + ((size_t)(seg * ODIM + colB0 + wave * 16 + lrow)) * IDIM + lk8;
  const unsigned short* gB1 = gB0 + (size_t)ODIM * IDIM;

  f32x4 acc0[4][2] = {};
  f32x4 acc1[4][2] = {};

  for (int kk = 0; kk < IDIM; kk += 64) {
    __syncthreads();                        // prior iter's LDS reads complete
#pragma unroll
    for (int h = 0; h < 2; h++) {
      int ko = kk + h * 32;
#pragma unroll
      for (int t = 0; t < 2; t++) {
        int r0 = (wave * 2 + t) * 16;       // 16 rows (1024 B) per issue
        async_cp16(Xb + (size_t)rid[t] * IDIM + ko + lk8, &As[h][r0 * 32]);
      }
      async_cp16(gB0 + ko, &Bs0[h][wave * 16 * 32]);
      async_cp16(gB1 + ko, &Bs1[h][wave * 16 * 32]);
    }
    __syncthreads();                        // staging visible (vmcnt drain at barrier)

#pragma unroll
    for (int h = 0; h < 2; h++) {
      frag8 af[4], bfr[2];
#pragma unroll
      for (int mi = 0; mi < 4; mi++)
        af[mi] = *(const frag8*)&As[h][(wm * 64 + mi * 16 + (lane & 15)) * 32 + (lane >> 4) * 8];
#pragma unroll
      for (int ni = 0; ni < 2; ni++)
        bfr[ni] = *(const frag8*)&Bs0[h][(wn * 32 + ni * 16 + (lane & 15)) * 32 + (lane >> 4) * 8];
#pragma unroll
      for (int mi = 0; mi < 4; mi++)
#pragma unroll
        for (int ni = 0; ni < 2; ni++)
          acc0[mi][ni] = __builtin_amdgcn_mfma_f32_16x16x32_bf16(af[mi], bfr[ni], acc0[mi][ni], 0, 0, 0);
#pragma unroll
      for (int ni = 0; ni < 2; ni++)
        bfr[ni] = *(const frag8*)&Bs1[h][(wn * 32 + ni * 16 + (lane & 15)) * 32 + (lane >> 4) * 8];
#pragma unroll
      for (int mi = 0; mi < 4; mi++)
#pragma unroll
        for (int ni = 0; ni < 2; ni++)
          acc1[mi][ni] = __builtin_amdgcn_mfma_f32_16x16x32_bf16(af[mi], bfr[ni], acc1[mi][ni], 0, 0, 0);
    }
  }

  // Epilogue: D col = lane&15, row = (lane>>4)*4 + reg  [m89/m91 verified]
  int   col[2]; float bv[2];
#pragma unroll
  for (int ni = 0; ni < 2; ni++) {
    col[ni] = colB0 + wn * 32 + ni * 16 + (lane & 15);
    bv[ni]  = bias[col[ni]];
  }
#pragma unroll
  for (int mi = 0; mi < 4; mi++) {
    int irow = wm * 64 + mi * 16 + (lane >> 4) * 4;
#pragma unroll
    for (int r = 0; r < 4; r++) {
      int idx = irow + r;
      if (idx < rlim) {                     // non-padding row
        int orow = rows[idx];
        float2 w = ws2[orow];
        float* o = out + (size_t)orow * ODIM;
#pragma unroll
        for (int ni = 0; ni < 2; ni++)
          o[col[ni]] = w.x * acc0[mi][ni][r] + w.y * acc1[mi][ni][r] + bv[ni];
      }
    }
  }
}

// ---------------- Fallback (ws too small): slow fp32, correct ----------------
__global__ void fallback_kernel(const float* __restrict__ x, const float* __restrict__ coeff,
                                const float* __restrict__ bias, float* __restrict__ out) {
  int b = blockIdx.x;
  int tid = threadIdx.x;
  __shared__ float xs[IDIM];
  __shared__ float ps[4];
  __shared__ float mw[2];
  __shared__ int   ms;
  float4 v = ((const float4*)(x + (size_t)b * IDIM))[tid];
  ((float4*)xs)[tid] = v;
  float s = v.x + v.y + v.z + v.w;
#pragma unroll
  for (int off = 32; off; off >>= 1) s += __shfl_down(s, off, 64);
  if ((tid & 63) == 0) ps[tid >> 6] = s;
  __syncthreads();
  if (tid == 0) {
    float m = (ps[0] + ps[1] + ps[2] + ps[3]) * (1.0f / (float)IDIM);
    int sI; float w0, w1;
    seg_weights(m, sI, w0, w1);
    mw[0] = w0; mw[1] = w1; ms = sI;
  }
  __syncthreads();
  float w0 = mw[0], w1 = mw[1]; int sI = ms;
  for (int o = tid; o < ODIM; o += 256) {
    const float* c0 = coeff + ((size_t)sI * ODIM + o) * IDIM;
    const float* c1 = c0 + (size_t)ODIM * IDIM;
    float a0 = 0.f, a1 = 0.f;
    for (int i = 0; i < IDIM; i++) { a0 += xs[i] * c0[i]; a1 += xs[i] * c1[i]; }
    out[(size_t)b * ODIM + o] = w0 * a0 + w1 * a1 + bias[o];
  }
}

extern "C" void kernel_launch(void* const* d_in, const int* in_sizes, int n_in,
                              void* d_out, int out_size, void* d_ws, size_t ws_size,
                              hipStream_t stream) {
  const float* x     = (const float*)d_in[0];
  const float* coeff = (const float*)d_in[1];
  const float* bias  = (const float*)d_in[2];
  float* out = (float*)d_out;

  // Workspace layout (16B-aligned chunks)
  size_t szXb = (size_t)B_ROWS * IDIM * sizeof(unsigned short);       // 33,554,432
  size_t szCb = (size_t)NGRID * ODIM * IDIM * sizeof(unsigned short); // 18,874,368
  size_t o0 = 0;
  unsigned short* Xb = (unsigned short*)((char*)d_ws + o0); o0 += szXb;
  unsigned short* Cb = (unsigned short*)((char*)d_ws + o0); o0 += szCb;
  float2* ws2 = (float2*)((char*)d_ws + o0); o0 += (size_t)B_ROWS * 8;
  int* seg_rows = (int*)((char*)d_ws + o0); o0 += (size_t)NGRID * B_ROWS * 4;
  int* bucket_cnt = (int*)((char*)d_ws + o0); o0 += 256;

  if (ws_size < o0) {
    // Emergency slow path: no workspace required.
    fallback_kernel<<<B_ROWS, 256, 0, stream>>>(x, coeff, bias, out);
    return;
  }

  zero_meta<<<1, 64, 0, stream>>>(bucket_cnt);
  row_stats_fused<<<RS_BLOCKS, 256, 0, stream>>>(x, Xb, ws2, seg_rows, bucket_cnt);
  cvt_coeff<<<NGRID * CV_BLKS_PER_PLANE, 256, 0, stream>>>(coeff, Cb, bucket_cnt);
  kan_gemm<<<GEMM_BLOCKS, 256, 0, stream>>>(Xb, Cb, seg_rows, bucket_cnt, ws2, bias, out);
}

// Round 7
// 232.853 us; speedup vs baseline: 2.0769x; 1.0068x over previous
//
#include <hip/hip_runtime.h>
#include <math.h>

// Problem constants
#define B_ROWS 16384      // 8*2048 batch rows
#define IDIM   1024
#define ODIM   1024
#define NGRID  9          // NUM_SEGMENTS + 1

#define RS_BLOCKS 1024
#define RS_ROWS   (B_ROWS / RS_BLOCKS)   // 16 rows per block

// GEMM grid: BM=128 BN=64 -> 16 n-tiles. 18 groups x 128 = 2304 blocks.
// Swizzle: within a 128-id window, (id&7) selects m-tile class -> the 16
// n-blocks of one m-tile share an XCD (round-robin dispatch) for A-tile L2 reuse.
#define GEMM_GROUPS 18
#define GEMM_BLOCKS (GEMM_GROUPS * 128)

typedef __attribute__((ext_vector_type(8))) short frag8;   // 8 x bf16 (4 VGPRs)
typedef __attribute__((ext_vector_type(4))) float f32x4;   // MFMA accumulator

typedef __attribute__((address_space(1))) void gvoid;
typedef __attribute__((address_space(3))) void lvoid;

__device__ __forceinline__ void async_cp16(const void* g, void* l) {
  // 16B/lane global->LDS DMA; LDS dest = wave-uniform base + lane*16.
  // Global side is a normal per-lane VMEM address (gather OK).
  __builtin_amdgcn_global_load_lds((gvoid*)(void*)g, (lvoid*)l, 16, 0, 0);
}

__device__ __forceinline__ unsigned short f2bf(float f) {
  union { float f; unsigned u; } v; v.f = f;
  unsigned u = v.u;
  u += 0x7fffu + ((u >> 16) & 1u);      // round-to-nearest-even
  return (unsigned short)(u >> 16);
}

// Per-row hat weights: at most 2 nonzero, at segments {s, s+1}
__device__ __forceinline__ void seg_weights(float m, int& sI, float& w0, float& w1) {
  float wsum = 0.f, wg[NGRID];
#pragma unroll
  for (int g = 0; g < NGRID; g++) {
    float gv = -1.f + 0.25f * (float)g;
    float t = 1.f - fabsf(m - gv) * 4.f;   // 1/h = 4
    wg[g] = t > 0.f ? t : 0.f;
    wsum += wg[g];
  }
  int s = (int)floorf((m + 1.f) * 4.f);
  s = s < 0 ? 0 : (s > 7 ? 7 : s);
  float inv = 1.f / (wsum + 1e-8f);
  sI = s;
  w0 = wg[s] * inv;
  w1 = wg[s + 1] * inv;
}

// ---------------- Pass 0: zero bucket counters ----------------
__global__ void zero_meta(int* bucket_cnt) {
  if (threadIdx.x < NGRID) bucket_cnt[threadIdx.x] = 0;
}

// ---------------- Pass 1 (fused): mean/weights/segment + bf16 cvt + seg lists --
// Each wave handles one row: data stays in registers, so the bf16 copy is
// written with NO re-read. Two-level atomic aggregation for ranks.
__global__ void row_stats_fused(const float* __restrict__ x,
                                unsigned short* __restrict__ Xb,
                                float2* __restrict__ ws2,
                                int* __restrict__ seg_rows,
                                int* __restrict__ bucket_cnt) {
  __shared__ int lcnt[NGRID];
  __shared__ int base[NGRID];
  __shared__ int lrank[RS_ROWS];
  __shared__ int lseg[RS_ROWS];
  const int tid  = threadIdx.x;          // 256 threads, 4 waves
  const int lane = tid & 63;
  const int wave = tid >> 6;
  if (tid < NGRID) lcnt[tid] = 0;
  __syncthreads();
  const int row0 = blockIdx.x * RS_ROWS;
#pragma unroll
  for (int it = 0; it < RS_ROWS / 4; ++it) {
    int r = it * 4 + wave;               // one wave per row
    int b = row0 + r;
    const float4* xr = (const float4*)(x + (size_t)b * IDIM);
    ushort4* xw = (ushort4*)(Xb + (size_t)b * IDIM);
    float4 v[4];
    float s = 0.f;
#pragma unroll
    for (int j = 0; j < 4; j++) {        // 4 independent 16B loads/lane
      v[j] = xr[lane + j * 64];
      s += v[j].x + v[j].y + v[j].z + v[j].w;
    }
#pragma unroll
    for (int j = 0; j < 4; j++) {        // bf16 copy straight from registers
      ushort4 u;
      u.x = f2bf(v[j].x); u.y = f2bf(v[j].y); u.z = f2bf(v[j].z); u.w = f2bf(v[j].w);
      xw[lane + j * 64] = u;
    }
#pragma unroll
    for (int off = 32; off; off >>= 1) s += __shfl_down(s, off, 64);
    if (lane == 0) {
      float m = s * (1.0f / (float)IDIM);
      int sI; float w0, w1;
      seg_weights(m, sI, w0, w1);
      ws2[b] = make_float2(w0, w1);
      lseg[r] = sI;
      lrank[r] = atomicAdd(&lcnt[sI], 1);   // LDS atomic: cheap
    }
  }
  __syncthreads();
  if (tid < NGRID) base[tid] = lcnt[tid] ? atomicAdd(&bucket_cnt[tid], lcnt[tid]) : 0;
  __syncthreads();
  if (tid < RS_ROWS)
    seg_rows[lseg[tid] * B_ROWS + base[lseg[tid]] + lrank[tid]] = row0 + tid;
}

// ---------------- Pass 2: coeff fp32 -> bf16, only planes actually needed ----
// Plane h is needed iff some non-empty bucket g has h in {g, g+1}.
#define CV_BLKS_PER_PLANE (ODIM * IDIM / 4 / 256)   // 1024
__global__ void cvt_coeff(const float* __restrict__ c, unsigned short* __restrict__ cb,
                          const int* __restrict__ bucket_cnt) {
  const int g  = blockIdx.x >> 10;            // plane 0..8
  const int cI = blockIdx.x & 1023;
  bool need = bucket_cnt[g] > 0;
  if (!need && g > 0) need = bucket_cnt[g - 1] > 0;
  if (!need) return;
  int i = (g * CV_BLKS_PER_PLANE + cI) * 256 + threadIdx.x;
  float4 v = ((const float4*)c)[i];
  ushort4 o;
  o.x = f2bf(v.x); o.y = f2bf(v.y); o.z = f2bf(v.z); o.w = f2bf(v.w);
  ((ushort4*)cb)[i] = o;
}

// ---------------- Pass 3: MFMA GEMM, dual-acc, BM=128 BN=64, BK=64, gather-A --
// acc0 = X[rows] @ coeff[seg]^T, acc1 = X[rows] @ coeff[seg+1]^T  (K=1024)
// out[row] = w0[row]*acc0 + w1[row]*acc1 + bias.  Rows gathered per-lane from
// unsorted bf16 Xb via seg_rows.
// Bank-conflict fix: k-chunk XOR swizzle. Staging lane l loads global chunk
// (l&3)^((l>>3)&3) of its row (same 64 B span -> coalescing unchanged);
// readers fetch chunk q^((r>>1)&3). Read bank = 16(r&1)+4(q^f(r)) -> every
// 16-lane phase = 8 banks x 2 lanes = free 2-way (m136).
__global__ void __launch_bounds__(256, 4)
kan_gemm(const unsigned short* __restrict__ Xb,
         const unsigned short* __restrict__ Cb,
         const int* __restrict__ seg_rows,
         const int* __restrict__ bucket_cnt,
         const float2* __restrict__ ws2,
         const float* __restrict__ bias,
         float* __restrict__ out) {
  // XCD swizzle: sub&7 -> m-tile class (same XCD), sub>>3 -> n-tile (0..15).
  const int sub = blockIdx.x & 127;
  const int mt  = (blockIdx.x >> 7) * 8 + (sub & 7);
  const int nt  = sub >> 3;

  // Map m-tile -> (segment, local tile, bucket count) from the 9 counters.
  int seg = -1, lt = 0, cnt = 0;
  {
    int t0 = 0;
#pragma unroll
    for (int g = 0; g < NGRID; g++) {
      int c   = bucket_cnt[g];
      int ntg = (c + 127) >> 7;
      if (mt >= t0 && mt < t0 + ntg) { seg = g; lt = mt - t0; cnt = c; }
      t0 += ntg;
    }
  }
  if (seg < 0) return;                      // uniform over block: barrier-safe
  const int rlim = cnt - lt * 128;          // valid rows in this tile (1..128)
  const int* rows = seg_rows + seg * B_ROWS + lt * 128;

  __shared__ unsigned short As[2][128 * 32];   // 16 KB
  __shared__ unsigned short Bs0[2][64 * 32];   // 8 KB
  __shared__ unsigned short Bs1[2][64 * 32];   // 8 KB

  const int tid  = threadIdx.x;
  const int lane = tid & 63;
  const int wave = tid >> 6;                // 4 waves, 2x2 over 128x64
  const int wm   = wave >> 1;               // 0..1 -> 64-row half
  const int wn   = wave & 1;                // 0..1 -> 32-col half
  const int colB0 = nt * 64;

  const int lrow = lane >> 2;               // 0..15 rows per 1KB issue
  // staging k-offset (shorts): XOR-swizzled chunk of this lane's row
  const int lswz = (((lane & 3) ^ ((lane >> 3) & 3))) * 8;
  // reader k-offset (shorts): un-swizzle for row r=lane&15, chunk q=lane>>4
  const int rswz = (((lane >> 4) ^ ((lane >> 1) & 3))) * 8;

  // Per-lane A-row ids for this wave's two 16-row staging groups (constant
  // over the K-loop). Clamp padding lanes to a valid row (masked at epilogue).
  int rid[2];
#pragma unroll
  for (int t = 0; t < 2; t++) {
    int idx = (wave * 2 + t) * 16 + lrow;
    rid[t] = rows[idx < rlim ? idx : rlim - 1];
  }

  // B staging: each wave loads one 16-row group of the 64-row B tiles.
  const unsigned short* gB0 = Cb + ((size_t)(seg * ODIM + colB0 + wave * 16 + lrow)) * IDIM + lswz;
  const unsigned short* gB1 = gB0 + (size_t)ODIM * IDIM;

  f32x4 acc0[4][2] = {};
  f32x4 acc1[4][2] = {};

  for (int kk = 0; kk < IDIM; kk += 64) {
    __syncthreads();                        // prior iter's LDS reads complete
#pragma unroll
    for (int h = 0; h < 2; h++) {
      int ko = kk + h * 32;
#pragma unroll
      for (int t = 0; t < 2; t++) {
        int r0 = (wave * 2 + t) * 16;       // 16 rows (1024 B) per issue
        async_cp16(Xb + (size_t)rid[t] * IDIM + ko + lswz, &As[h][r0 * 32]);
      }
      async_cp16(gB0 + ko, &Bs0[h][wave * 16 * 32]);
      async_cp16(gB1 + ko, &Bs1[h][wave * 16 * 32]);
    }
    __syncthreads();                        // staging visible (vmcnt drain at barrier)

#pragma unroll
    for (int h = 0; h < 2; h++) {
      frag8 af[4], bfr[2];
#pragma unroll
      for (int mi = 0; mi < 4; mi++)
        af[mi] = *(const frag8*)&As[h][(wm * 4 + mi) * 512 + (lane & 15) * 32 + rswz];
#pragma unroll
      for (int ni = 0; ni < 2; ni++)
        bfr[ni] = *(const frag8*)&Bs0[h][(wn * 2 + ni) * 512 + (lane & 15) * 32 + rswz];
#pragma unroll
      for (int mi = 0; mi < 4; mi++)
#pragma unroll
        for (int ni = 0; ni < 2; ni++)
          acc0[mi][ni] = __builtin_amdgcn_mfma_f32_16x16x32_bf16(af[mi], bfr[ni], acc0[mi][ni], 0, 0, 0);
#pragma unroll
      for (int ni = 0; ni < 2; ni++)
        bfr[ni] = *(const frag8*)&Bs1[h][(wn * 2 + ni) * 512 + (lane & 15) * 32 + rswz];
#pragma unroll
      for (int mi = 0; mi < 4; mi++)
#pragma unroll
        for (int ni = 0; ni < 2; ni++)
          acc1[mi][ni] = __builtin_amdgcn_mfma_f32_16x16x32_bf16(af[mi], bfr[ni], acc1[mi][ni], 0, 0, 0);
    }
  }

  // Epilogue: D col = lane&15, row = (lane>>4)*4 + reg  [m89/m91 verified]
  int   col[2]; float bv[2];
#pragma unroll
  for (int ni = 0; ni < 2; ni++) {
    col[ni] = colB0 + wn * 32 + ni * 16 + (lane & 15);
    bv[ni]  = bias[col[ni]];
  }
#pragma unroll
  for (int mi = 0; mi < 4; mi++) {
    int irow = wm * 64 + mi * 16 + (lane >> 4) * 4;
#pragma unroll
    for (int r = 0; r < 4; r++) {
      int idx = irow + r;
      if (idx < rlim) {                     // non-padding row
        int orow = rows[idx];
        float2 w = ws2[orow];
        float* o = out + (size_t)orow * ODIM;
#pragma unroll
        for (int ni = 0; ni < 2; ni++)
          o[col[ni]] = w.x * acc0[mi][ni][r] + w.y * acc1[mi][ni][r] + bv[ni];
      }
    }
  }
}

// ---------------- Fallback (ws too small): slow fp32, correct ----------------
__global__ void fallback_kernel(const float* __restrict__ x, const float* __restrict__ coeff,
                                const float* __restrict__ bias, float* __restrict__ out) {
  int b = blockIdx.x;
  int tid = threadIdx.x;
  __shared__ float xs[IDIM];
  __shared__ float ps[4];
  __shared__ float mw[2];
  __shared__ int   ms;
  float4 v = ((const float4*)(x + (size_t)b * IDIM))[tid];
  ((float4*)xs)[tid] = v;
  float s = v.x + v.y + v.z + v.w;
#pragma unroll
  for (int off = 32; off; off >>= 1) s += __shfl_down(s, off, 64);
  if ((tid & 63) == 0) ps[tid >> 6] = s;
  __syncthreads();
  if (tid == 0) {
    float m = (ps[0] + ps[1] + ps[2] + ps[3]) * (1.0f / (float)IDIM);
    int sI; float w0, w1;
    seg_weights(m, sI, w0, w1);
    mw[0] = w0; mw[1] = w1; ms = sI;
  }
  __syncthreads();
  float w0 = mw[0], w1 = mw[1]; int sI = ms;
  for (int o = tid; o < ODIM; o += 256) {
    const float* c0 = coeff + ((size_t)sI * ODIM + o) * IDIM;
    const float* c1 = c0 + (size_t)ODIM * IDIM;
    float a0 = 0.f, a1 = 0.f;
    for (int i = 0; i < IDIM; i++) { a0 += xs[i] * c0[i]; a1 += xs[i] * c1[i]; }
    out[(size_t)b * ODIM + o] = w0 * a0 + w1 * a1 + bias[o];
  }
}

extern "C" void kernel_launch(void* const* d_in, const int* in_sizes, int n_in,
                              void* d_out, int out_size, void* d_ws, size_t ws_size,
                              hipStream_t stream) {
  const float* x     = (const float*)d_in[0];
  const float* coeff = (const float*)d_in[1];
  const float* bias  = (const float*)d_in[2];
  float* out = (float*)d_out;

  // Workspace layout (16B-aligned chunks)
  size_t szXb = (size_t)B_ROWS * IDIM * sizeof(unsigned short);       // 33,554,432
  size_t szCb = (size_t)NGRID * ODIM * IDIM * sizeof(unsigned short); // 18,874,368
  size_t o0 = 0;
  unsigned short* Xb = (unsigned short*)((char*)d_ws + o0); o0 += szXb;
  unsigned short* Cb = (unsigned short*)((char*)d_ws + o0); o0 += szCb;
  float2* ws2 = (float2*)((char*)d_ws + o0); o0 += (size_t)B_ROWS * 8;
  int* seg_rows = (int*)((char*)d_ws + o0); o0 += (size_t)NGRID * B_ROWS * 4;
  int* bucket_cnt = (int*)((char*)d_ws + o0); o0 += 256;

  if (ws_size < o0) {
    // Emergency slow path: no workspace required.
    fallback_kernel<<<B_ROWS, 256, 0, stream>>>(x, coeff, bias, out);
    return;
  }

  zero_meta<<<1, 64, 0, stream>>>(bucket_cnt);
  row_stats_fused<<<RS_BLOCKS, 256, 0, stream>>>(x, Xb, ws2, seg_rows, bucket_cnt);
  cvt_coeff<<<NGRID * CV_BLKS_PER_PLANE, 256, 0, stream>>>(coeff, Cb, bucket_cnt);
  kan_gemm<<<GEMM_BLOCKS, 256, 0, stream>>>(Xb, Cb, seg_rows, bucket_cnt, ws2, bias, out);
}